// Round 10
// baseline (335.398 us; speedup 1.0000x reference)
//
#include <hip/hip_runtime.h>

#define Bb 64
#define Ss 1000
#define Kk 12
#define Nn 80
#define CTERM 73.51508265637381f   // 0.5 * 80 * log(2*pi)
#define STA 84                     // fp32 LDS stride (336 B, 16B-aligned)

typedef __attribute__((ext_vector_type(8))) short short8;
typedef __attribute__((ext_vector_type(4))) float f32x4;

static __device__ __forceinline__ unsigned short f2bf(float f) {
    unsigned u = __builtin_bit_cast(unsigned, f);
    unsigned r = u + 0x7FFFu + ((u >> 16) & 1u);   // round-to-nearest-even
    return (unsigned short)(r >> 16);
}
static __device__ __forceinline__ float bf2f(unsigned short h) {
    unsigned u = ((unsigned)h) << 16;
    return __builtin_bit_cast(float, u);
}

// ============ R10: FUSED single kernel — prep (R7 8-wave, validated) + MFMA ll =========
// One block per (b,k), 512 threads. Phase 1: R7's rotating-master Cholesky + inversion +
// v (verbatim math). W fragments packed into LDS (not global). Phase 2: 8 waves compute
// the (b,k) log-likelihood slice with in-register x->bf16 conversion (mid-tier pattern).
// Eliminates: 2nd launch, W global round-trip (39 MB), X workspace pipeline (50 MB+32 MB).
// LDS 53.5 KB -> 3 blocks/CU; launch_bounds(512,6) keeps VGPR <= ~85 for 24 waves/CU.
// Grid dim3(Bb,Kk): b fastest -> same-b blocks on one XCD share x[b] in L2.
__global__ __launch_bounds__(512, 6) void fused_ll_kernel(
    const float* __restrict__ sigma, const float* __restrict__ mu,
    const float* __restrict__ x, float* __restrict__ out)
{
    __shared__ float Ls[Nn * STA];       // A: working matrix; B: lower=L, upper=W^T
    __shared__ uint4 WhL[800], WlL[800]; // packed W frags (hi/lo); early: vps scratch
    __shared__ float invd[Nn];
    __shared__ float mus[Nn];
    __shared__ float vls[Nn];            // v = W*mu
    __shared__ float ldp[8];
    __shared__ float lds_ld;             // logdet

    const int b   = blockIdx.x;
    const int k   = blockIdx.y;
    const int bk  = b * Kk + k;
    const int tid = threadIdx.x;
    const int w   = tid >> 6;        // 0..7
    const int l   = tid & 63;
    const int r2  = l + 64;

    // ---- stage sigma: lower + diag-block only (c4 <= r+3) ----
    const float4* sp4 = (const float4*)(sigma + (size_t)bk * Nn * Nn);
    #pragma unroll
    for (int it = 0; it < 4; ++it) {
        int ci = tid + 512 * it;
        if (ci < 1600) {
            int r = ci / 20, c4 = 4 * (ci - 20 * r);
            if (c4 <= r + 3) {
                float4 v = sp4[ci];
                *(float4*)&Ls[r * STA + c4] = v;
            }
        }
    }
    if (tid < Nn) mus[tid] = mu[(size_t)bk * Nn + tid];
    __syncthreads();
    if (tid < Nn) Ls[tid * STA + tid] += 1e-5f;
    __syncthreads();

    // ---- Phase A: blocked Cholesky; master = wave (p&7); 1 barrier/panel ----
    float ldacc = 0.0f;
    for (int p = 0; p < 20; ++p) {
        const int j0 = 4 * p;
        const bool a1 = (l >= j0);
        const bool a2 = (l < 16) && (r2 >= j0);

        if (w == (p & 7)) {
            float B00 = Ls[j0*STA+j0];
            float B10 = Ls[(j0+1)*STA+j0], B11 = Ls[(j0+1)*STA+j0+1];
            float B20 = Ls[(j0+2)*STA+j0], B21 = Ls[(j0+2)*STA+j0+1], B22 = Ls[(j0+2)*STA+j0+2];
            float B30 = Ls[(j0+3)*STA+j0], B31 = Ls[(j0+3)*STA+j0+1], B32 = Ls[(j0+3)*STA+j0+2], B33 = Ls[(j0+3)*STA+j0+3];
            float rv0 = rsqrtf(B00);
            float l10 = B10*rv0, l20 = B20*rv0, l30 = B30*rv0;
            float t11 = fmaf(-l10,l10,B11);                    float rv1 = rsqrtf(t11);
            float l21 = fmaf(-l20,l10,B21)*rv1;
            float l31 = fmaf(-l30,l10,B31)*rv1;
            float t22 = fmaf(-l21,l21,fmaf(-l20,l20,B22));     float rv2 = rsqrtf(t22);
            float l32 = fmaf(-l31,l21,fmaf(-l30,l20,B32))*rv2;
            float t33 = fmaf(-l32,l32,fmaf(-l31,l31,fmaf(-l30,l30,B33)));
            float rv3 = rsqrtf(t33);
            ldacc += 0.5f * (logf(B00) + logf(t11) + logf(t22) + logf(t33));
            if (l == 0) { invd[j0]=rv0; invd[j0+1]=rv1; invd[j0+2]=rv2; invd[j0+3]=rv3; }

            if (a1) {
                float4 a = *(float4*)&Ls[l * STA + j0];
                float b0 = a.x * rv0;
                float b1 = fmaf(-l10, b0, a.y) * rv1;
                float b2 = fmaf(-l21, b1, fmaf(-l20, b0, a.z)) * rv2;
                float b3 = fmaf(-l32, b2, fmaf(-l31, b1, fmaf(-l30, b0, a.w))) * rv3;
                *(float4*)&Ls[l * STA + j0] = make_float4(b0, b1, b2, b3);
            }
            if (a2) {
                float4 a = *(float4*)&Ls[r2 * STA + j0];
                float c0 = a.x * rv0;
                float c1 = fmaf(-l10, c0, a.y) * rv1;
                float c2 = fmaf(-l21, c1, fmaf(-l20, c0, a.z)) * rv2;
                float c3 = fmaf(-l32, c2, fmaf(-l31, c1, fmaf(-l30, c0, a.w))) * rv3;
                *(float4*)&Ls[r2 * STA + j0] = make_float4(c0, c1, c2, c3);
            }
        }
        __syncthreads();   // publish panel solve; the ONLY barrier this panel

        // lower-only update of owned groups (g ≡ w mod 8, g > p); lane l -> row 4g+l
        const int gs0 = p + 1;
        const int g0 = gs0 + ((w - gs0) & 7);
        #pragma unroll 2
        for (int g = g0; g < 20; g += 8) {
            const int cb = 4 * g;
            float4 q0 = *(const float4*)&Ls[(cb+0) * STA + j0];   // L[cb+c][j0..j0+3]
            float4 q1 = *(const float4*)&Ls[(cb+1) * STA + j0];
            float4 q2 = *(const float4*)&Ls[(cb+2) * STA + j0];
            float4 q3 = *(const float4*)&Ls[(cb+3) * STA + j0];
            {
                const int R = cb + l;                              // rows cb..cb+63
                if (R < Nn) {
                    float4 pv = *(const float4*)&Ls[R * STA + j0];
                    float4 t  = *(float4*)&Ls[R * STA + cb];
                    t.x = fmaf(-pv.x,q0.x, fmaf(-pv.y,q0.y, fmaf(-pv.z,q0.z, fmaf(-pv.w,q0.w, t.x))));
                    t.y = fmaf(-pv.x,q1.x, fmaf(-pv.y,q1.y, fmaf(-pv.z,q1.z, fmaf(-pv.w,q1.w, t.y))));
                    t.z = fmaf(-pv.x,q2.x, fmaf(-pv.y,q2.y, fmaf(-pv.z,q2.z, fmaf(-pv.w,q2.w, t.z))));
                    t.w = fmaf(-pv.x,q3.x, fmaf(-pv.y,q3.y, fmaf(-pv.z,q3.z, fmaf(-pv.w,q3.w, t.w))));
                    *(float4*)&Ls[R * STA + cb] = t;
                }
            }
            if (cb + 64 < Nn) {                                    // tail rows cb+64..79 (g<4)
                const int R = cb + 64 + l;
                if (R < Nn) {
                    float4 pv = *(const float4*)&Ls[R * STA + j0];
                    float4 t  = *(float4*)&Ls[R * STA + cb];
                    t.x = fmaf(-pv.x,q0.x, fmaf(-pv.y,q0.y, fmaf(-pv.z,q0.z, fmaf(-pv.w,q0.w, t.x))));
                    t.y = fmaf(-pv.x,q1.x, fmaf(-pv.y,q1.y, fmaf(-pv.z,q1.z, fmaf(-pv.w,q1.w, t.y))));
                    t.z = fmaf(-pv.x,q2.x, fmaf(-pv.y,q2.y, fmaf(-pv.z,q2.z, fmaf(-pv.w,q2.w, t.z))));
                    t.w = fmaf(-pv.x,q3.x, fmaf(-pv.y,q3.y, fmaf(-pv.z,q3.z, fmaf(-pv.w,q3.w, t.w))));
                    *(float4*)&Ls[R * STA + cb] = t;
                }
            }
        }
    }
    if (l == 0) ldp[w] = ldacc;
    __syncthreads();
    if (tid == 0) lds_ld = ldp[0]+ldp[1]+ldp[2]+ldp[3]+ldp[4]+ldp[5]+ldp[6]+ldp[7];

    // ---- A->B transition: zero strict-upper storage (W^T region); lower keeps L ----
    for (int i = tid; i < Nn * Nn; i += 512) {
        int r = i / Nn, c = i - Nn * r;
        if (c > r) Ls[r * STA + c] = 0.0f;
    }
    __syncthreads();

    // ---- Phase B: triangular inversion into storage-upper; L read from storage-lower --
    for (int p = 0; p < 20; ++p) {
        const int i0 = 4 * p;
        const bool b1a = (i0 + 3 >= l);
        const bool b2a = (l < 16) && (i0 + 3 >= r2);

        if (w == (p & 7)) {
            float m10 = Ls[(i0+1)*STA + i0];
            float m20 = Ls[(i0+2)*STA + i0];
            float m30 = Ls[(i0+3)*STA + i0];
            float m21 = Ls[(i0+2)*STA + i0+1];
            float m31 = Ls[(i0+3)*STA + i0+1];
            float m32 = Ls[(i0+3)*STA + i0+2];
            float4 iv = *(const float4*)&invd[i0];
            if (b1a) {
                float4 a = *(float4*)&Ls[l * STA + i0];
                if (l >= i0)   // virtual identity rows (diag block)
                    a = make_float4(l==i0?1.f:0.f, l==i0+1?1.f:0.f, l==i0+2?1.f:0.f, l==i0+3?1.f:0.f);
                float w0 = a.x * iv.x;
                float w1 = fmaf(-w0, m10, a.y) * iv.y;
                float w2 = fmaf(-w1, m21, fmaf(-w0, m20, a.z)) * iv.z;
                float w3 = fmaf(-w2, m32, fmaf(-w1, m31, fmaf(-w0, m30, a.w))) * iv.w;
                *(float4*)&Ls[l * STA + i0] = make_float4(w0, w1, w2, w3);
            }
            if (b2a) {
                float4 a = *(float4*)&Ls[r2 * STA + i0];
                if (r2 >= i0)
                    a = make_float4(r2==i0?1.f:0.f, r2==i0+1?1.f:0.f, r2==i0+2?1.f:0.f, r2==i0+3?1.f:0.f);
                float v0 = a.x * iv.x;
                float v1 = fmaf(-v0, m10, a.y) * iv.y;
                float v2 = fmaf(-v1, m21, fmaf(-v0, m20, a.z)) * iv.z;
                float v3 = fmaf(-v2, m32, fmaf(-v1, m31, fmaf(-v0, m30, a.w))) * iv.w;
                *(float4*)&Ls[r2 * STA + i0] = make_float4(v0, v1, v2, v3);
            }
        }
        __syncthreads();   // publish panel solve

        float4 wv = make_float4(0.f,0.f,0.f,0.f), vv = make_float4(0.f,0.f,0.f,0.f);
        if (b1a) wv = *(float4*)&Ls[l * STA + i0];
        if (b2a) vv = *(float4*)&Ls[r2 * STA + i0];
        if (b1a | b2a) {
            const int gs0 = p + 1;
            const int g0 = gs0 + ((w - gs0) & 7);
            for (int g = g0; g < 20; g += 8) {
                float4 q0 = *(const float4*)&Ls[(4*g+0) * STA + i0];  // L[4g+0][i0..i0+3]
                float4 q1 = *(const float4*)&Ls[(4*g+1) * STA + i0];
                float4 q2 = *(const float4*)&Ls[(4*g+2) * STA + i0];
                float4 q3 = *(const float4*)&Ls[(4*g+3) * STA + i0];
                if (b1a) {
                    float4 t = *(float4*)&Ls[l * STA + 4*g];
                    t.x = fmaf(-wv.x,q0.x, fmaf(-wv.y,q0.y, fmaf(-wv.z,q0.z, fmaf(-wv.w,q0.w, t.x))));
                    t.y = fmaf(-wv.x,q1.x, fmaf(-wv.y,q1.y, fmaf(-wv.z,q1.z, fmaf(-wv.w,q1.w, t.y))));
                    t.z = fmaf(-wv.x,q2.x, fmaf(-wv.y,q2.y, fmaf(-wv.z,q2.z, fmaf(-wv.w,q2.w, t.z))));
                    t.w = fmaf(-wv.x,q3.x, fmaf(-wv.y,q3.y, fmaf(-wv.z,q3.z, fmaf(-wv.w,q3.w, t.w))));
                    *(float4*)&Ls[l * STA + 4*g] = t;
                }
                if (b2a) {
                    float4 t = *(float4*)&Ls[r2 * STA + 4*g];
                    t.x = fmaf(-vv.x,q0.x, fmaf(-vv.y,q0.y, fmaf(-vv.z,q0.z, fmaf(-vv.w,q0.w, t.x))));
                    t.y = fmaf(-vv.x,q1.x, fmaf(-vv.y,q1.y, fmaf(-vv.z,q1.z, fmaf(-vv.w,q1.w, t.y))));
                    t.z = fmaf(-vv.x,q2.x, fmaf(-vv.y,q2.y, fmaf(-vv.z,q2.z, fmaf(-vv.w,q2.w, t.z))));
                    t.w = fmaf(-vv.x,q3.x, fmaf(-vv.y,q3.y, fmaf(-vv.z,q3.z, fmaf(-vv.w,q3.w, t.w))));
                    *(float4*)&Ls[r2 * STA + 4*g] = t;
                }
            }
        }
    }
    __syncthreads();

    // ---- Phase C: v = W*mu (mask c<=row; storage-lower holds L) -> vls ----
    {
        float* vps = (float*)WhL;   // WhL area free until pack
        float s1 = 0.f, s2 = 0.f;
        const int c0 = 10 * w;
        #pragma unroll 2
        for (int cc = 0; cc < 10; ++cc) {
            int c = c0 + cc;
            float mc = mus[c];
            float e1 = (c <= l)  ? Ls[c * STA + l]  : 0.f;   // W[l][c]
            s1 = fmaf(e1, mc, s1);
            if (l < 16) {
                float e2 = (c <= r2) ? Ls[c * STA + r2] : 0.f;
                s2 = fmaf(e2, mc, s2);
            }
        }
        vps[w * Nn + l] = s1;
        if (l < 16) vps[w * Nn + r2] = s2;
        __syncthreads();
        if (tid < Nn) {
            float acc = 0.f;
            #pragma unroll
            for (int ww = 0; ww < 8; ++ww) acc += vps[ww * Nn + tid];
            vls[tid] = acc;
        }
        __syncthreads();   // vps reads done before pack overwrites WhL
    }

    // ---- Fragment pack into LDS (mask m>=kb+j; split 8 ways) ----
    const int n = l & 15, quad = l >> 4;
    for (int f = w; f < 10; f += 8) {
        int ks = f / 5, mt = f - 5 * ks;
        int m = 16 * mt + n, kb = 32 * ks + 8 * quad;
        unsigned hh[8], lo[8];
        #pragma unroll
        for (int j = 0; j < 8; ++j) {
            float wj = (m >= kb + j) ? Ls[(kb + j) * STA + m] : 0.f;   // = W[m][kb+j]
            unsigned short h = f2bf(wj);
            hh[j] = h; lo[j] = f2bf(wj - bf2f(h));
        }
        WhL[f*64 + l] = make_uint4(hh[0]|(hh[1]<<16), hh[2]|(hh[3]<<16), hh[4]|(hh[5]<<16), hh[6]|(hh[7]<<16));
        WlL[f*64 + l] = make_uint4(lo[0]|(lo[1]<<16), lo[2]|(lo[3]<<16), lo[4]|(lo[5]<<16), lo[6]|(lo[7]<<16));
    }
    if (w < 5) {
        int mt = w;
        if (quad < 2) {
            int m = 16 * mt + n, kb = 64 + 8 * quad;
            unsigned hh[8], lo[8];
            #pragma unroll
            for (int j = 0; j < 8; ++j) {
                float wj = (m >= kb + j) ? Ls[(kb + j) * STA + m] : 0.f;
                unsigned short h = f2bf(wj);
                hh[j] = h; lo[j] = f2bf(wj - bf2f(h));
            }
            WhL[640 + mt*32 + l] = make_uint4(hh[0]|(hh[1]<<16), hh[2]|(hh[3]<<16), hh[4]|(hh[5]<<16), hh[6]|(hh[7]<<16));
            WlL[640 + mt*32 + l] = make_uint4(lo[0]|(lo[1]<<16), lo[2]|(lo[3]<<16), lo[4]|(lo[5]<<16), lo[6]|(lo[7]<<16));
        }
    }
    __syncthreads();   // W frags + vls + lds_ld published

    // ---- Phase 2: MFMA log-likelihood; wave w covers sg = it*8 + w (16 s-rows each) ----
    const float ld = lds_ld;
    for (int it = 0; it < 8; ++it) {
        const int sg = it * 8 + w;
        const int gs = sg * 16 + n;

        // in-register x -> bf16 hi/lo B-fragments (mid-tier pattern)
        short8 bh[3], bl[3];
        #pragma unroll
        for (int ks = 0; ks < 3; ++ks) {
            int kb = 32 * ks + 8 * quad;
            float d[8] = {0.f,0.f,0.f,0.f,0.f,0.f,0.f,0.f};
            if (gs < Ss && kb < Nn) {
                const float* xp = x + ((size_t)b * Ss + gs) * Nn + kb;
                float4 f0 = *(const float4*)xp;
                float4 f1 = *(const float4*)(xp + 4);
                d[0]=f0.x; d[1]=f0.y; d[2]=f0.z; d[3]=f0.w;
                d[4]=f1.x; d[5]=f1.y; d[6]=f1.z; d[7]=f1.w;
            }
            short8 h, lo2;
            #pragma unroll
            for (int j = 0; j < 8; ++j) {
                unsigned short hv = f2bf(d[j]);
                h[j]   = (short)hv;
                lo2[j] = (short)f2bf(d[j] - bf2f(hv));
            }
            bh[ks] = h; bl[ks] = lo2;
        }

        f32x4 acc[5];
        #pragma unroll
        for (int mt = 0; mt < 5; ++mt) acc[mt] = (f32x4){0.f,0.f,0.f,0.f};

        #pragma unroll
        for (int ks = 0; ks < 3; ++ks) {
            #pragma unroll
            for (int mt = 0; mt < 5; ++mt) {
                short8 wh, wl;
                if (ks < 2) {
                    wh = __builtin_bit_cast(short8, WhL[(ks*5 + mt)*64 + l]);
                    wl = __builtin_bit_cast(short8, WlL[(ks*5 + mt)*64 + l]);
                } else {
                    uint4 zh = make_uint4(0,0,0,0), zl = make_uint4(0,0,0,0);
                    if (quad < 2) {
                        zh = WhL[640 + mt*32 + l];
                        zl = WlL[640 + mt*32 + l];
                    }
                    wh = __builtin_bit_cast(short8, zh);
                    wl = __builtin_bit_cast(short8, zl);
                }
                acc[mt] = __builtin_amdgcn_mfma_f32_16x16x32_bf16(wh, bh[ks], acc[mt], 0, 0, 0);
                acc[mt] = __builtin_amdgcn_mfma_f32_16x16x32_bf16(wl, bh[ks], acc[mt], 0, 0, 0);
                acc[mt] = __builtin_amdgcn_mfma_f32_16x16x32_bf16(wh, bl[ks], acc[mt], 0, 0, 0);
            }
        }

        float q2 = 0.f;
        #pragma unroll
        for (int mt = 0; mt < 5; ++mt) {
            f32x4 vfm = *(const f32x4*)&vls[16*mt + 4*quad];
            #pragma unroll
            for (int r = 0; r < 4; ++r) {
                float y = acc[mt][r] - vfm[r];
                q2 = fmaf(y, y, q2);
            }
        }
        q2 += __shfl_xor(q2, 16, 64);
        q2 += __shfl_xor(q2, 32, 64);
        if (l < 16 && gs < Ss)
            out[((size_t)b * Ss + gs) * Kk + k] = -0.5f * q2 - ld - CTERM;
    }
}

extern "C" void kernel_launch(void* const* d_in, const int* in_sizes, int n_in,
                              void* d_out, int out_size, void* d_ws, size_t ws_size,
                              hipStream_t stream) {
    const float* x     = (const float*)d_in[0];
    const float* mu    = (const float*)d_in[1];
    const float* sigma = (const float*)d_in[2];
    float* out = (float*)d_out;
    (void)d_ws; (void)ws_size;

    fused_ll_kernel<<<dim3(Bb, Kk), dim3(512), 0, stream>>>(sigma, mu, x, out);
}

// Round 11
// 157.793 us; speedup vs baseline: 2.1256x; 2.1256x over previous
//
#include <hip/hip_runtime.h>

#define Bb 64
#define Ss 1000
#define Kk 12
#define Nn 80
#define CTERM 73.51508265637381f   // 0.5 * 80 * log(2*pi)
#define STA 84                     // fp32 LDS stride (336 B, 16B-aligned)

typedef __attribute__((ext_vector_type(8))) short short8;
typedef __attribute__((ext_vector_type(4))) float f32x4;

static __device__ __forceinline__ unsigned short f2bf(float f) {
    unsigned u = __builtin_bit_cast(unsigned, f);
    unsigned r = u + 0x7FFFu + ((u >> 16) & 1u);   // round-to-nearest-even
    return (unsigned short)(r >> 16);
}
static __device__ __forceinline__ float bf2f(unsigned short h) {
    unsigned u = ((unsigned)h) << 16;
    return __builtin_bit_cast(float, u);
}

// ============ Kernel 1 (R7-validated): 8-wave prep, lower-triangle-only Phase A ========
// ~58 us measured (R7/R9). R10's fused variant regressed (HBM-bound, 851 MB) — reverted.
__global__ __launch_bounds__(512, 6) void prep_kernel(
    const float* __restrict__ sigma, const float* __restrict__ mu,
    const float* __restrict__ x,
    uint4* __restrict__ wsWh, uint4* __restrict__ wsWl,   // [768][800] uint4
    float* __restrict__ wsV, float* __restrict__ wsL,
    uint4* __restrict__ Xh, uint4* __restrict__ Xl, int doX)
{
    __shared__ float Ls[Nn * STA];   // A: working matrix; B: lower=L, upper=W^T
    __shared__ float invd[Nn];
    __shared__ float mus[Nn];
    __shared__ float ldp[8];
    __shared__ float vps[8 * Nn];    // Phase C partial v

    const int bk  = blockIdx.x;
    const int tid = threadIdx.x;
    const int w   = tid >> 6;        // 0..7
    const int l   = tid & 63;
    const int r2  = l + 64;

    // ---- stage sigma: lower + diag-block only (c4 <= r+3) ----
    const float4* sp4 = (const float4*)(sigma + (size_t)bk * Nn * Nn);
    #pragma unroll
    for (int it = 0; it < 4; ++it) {
        int ci = tid + 512 * it;
        if (ci < 1600) {
            int r = ci / 20, c4 = 4 * (ci - 20 * r);
            if (c4 <= r + 3) {
                float4 v = sp4[ci];
                *(float4*)&Ls[r * STA + c4] = v;
            }
        }
    }
    if (tid < Nn) mus[tid] = mu[(size_t)bk * Nn + tid];
    __syncthreads();
    if (tid < Nn) Ls[tid * STA + tid] += 1e-5f;
    __syncthreads();

    // ---- Phase A: blocked Cholesky; master = wave (p&7); 1 barrier/panel ----
    float ldacc = 0.0f;
    for (int p = 0; p < 20; ++p) {
        const int j0 = 4 * p;
        const bool a1 = (l >= j0);
        const bool a2 = (l < 16) && (r2 >= j0);

        if (w == (p & 7)) {
            float B00 = Ls[j0*STA+j0];
            float B10 = Ls[(j0+1)*STA+j0], B11 = Ls[(j0+1)*STA+j0+1];
            float B20 = Ls[(j0+2)*STA+j0], B21 = Ls[(j0+2)*STA+j0+1], B22 = Ls[(j0+2)*STA+j0+2];
            float B30 = Ls[(j0+3)*STA+j0], B31 = Ls[(j0+3)*STA+j0+1], B32 = Ls[(j0+3)*STA+j0+2], B33 = Ls[(j0+3)*STA+j0+3];
            float rv0 = rsqrtf(B00);
            float l10 = B10*rv0, l20 = B20*rv0, l30 = B30*rv0;
            float t11 = fmaf(-l10,l10,B11);                    float rv1 = rsqrtf(t11);
            float l21 = fmaf(-l20,l10,B21)*rv1;
            float l31 = fmaf(-l30,l10,B31)*rv1;
            float t22 = fmaf(-l21,l21,fmaf(-l20,l20,B22));     float rv2 = rsqrtf(t22);
            float l32 = fmaf(-l31,l21,fmaf(-l30,l20,B32))*rv2;
            float t33 = fmaf(-l32,l32,fmaf(-l31,l31,fmaf(-l30,l30,B33)));
            float rv3 = rsqrtf(t33);
            ldacc += 0.5f * (logf(B00) + logf(t11) + logf(t22) + logf(t33));
            if (l == 0) { invd[j0]=rv0; invd[j0+1]=rv1; invd[j0+2]=rv2; invd[j0+3]=rv3; }

            if (a1) {
                float4 a = *(float4*)&Ls[l * STA + j0];
                float b0 = a.x * rv0;
                float b1 = fmaf(-l10, b0, a.y) * rv1;
                float b2 = fmaf(-l21, b1, fmaf(-l20, b0, a.z)) * rv2;
                float b3 = fmaf(-l32, b2, fmaf(-l31, b1, fmaf(-l30, b0, a.w))) * rv3;
                *(float4*)&Ls[l * STA + j0] = make_float4(b0, b1, b2, b3);
            }
            if (a2) {
                float4 a = *(float4*)&Ls[r2 * STA + j0];
                float c0 = a.x * rv0;
                float c1 = fmaf(-l10, c0, a.y) * rv1;
                float c2 = fmaf(-l21, c1, fmaf(-l20, c0, a.z)) * rv2;
                float c3 = fmaf(-l32, c2, fmaf(-l31, c1, fmaf(-l30, c0, a.w))) * rv3;
                *(float4*)&Ls[r2 * STA + j0] = make_float4(c0, c1, c2, c3);
            }
        }
        __syncthreads();   // publish panel solve; the ONLY barrier this panel

        // lower-only update of owned groups (g ≡ w mod 8, g > p); lane l -> row 4g+l
        const int gs0 = p + 1;
        const int g0 = gs0 + ((w - gs0) & 7);
        #pragma unroll 2
        for (int g = g0; g < 20; g += 8) {
            const int cb = 4 * g;
            float4 q0 = *(const float4*)&Ls[(cb+0) * STA + j0];   // L[cb+c][j0..j0+3]
            float4 q1 = *(const float4*)&Ls[(cb+1) * STA + j0];
            float4 q2 = *(const float4*)&Ls[(cb+2) * STA + j0];
            float4 q3 = *(const float4*)&Ls[(cb+3) * STA + j0];
            {
                const int R = cb + l;                              // rows cb..cb+63
                if (R < Nn) {
                    float4 pv = *(const float4*)&Ls[R * STA + j0];
                    float4 t  = *(float4*)&Ls[R * STA + cb];
                    t.x = fmaf(-pv.x,q0.x, fmaf(-pv.y,q0.y, fmaf(-pv.z,q0.z, fmaf(-pv.w,q0.w, t.x))));
                    t.y = fmaf(-pv.x,q1.x, fmaf(-pv.y,q1.y, fmaf(-pv.z,q1.z, fmaf(-pv.w,q1.w, t.y))));
                    t.z = fmaf(-pv.x,q2.x, fmaf(-pv.y,q2.y, fmaf(-pv.z,q2.z, fmaf(-pv.w,q2.w, t.z))));
                    t.w = fmaf(-pv.x,q3.x, fmaf(-pv.y,q3.y, fmaf(-pv.z,q3.z, fmaf(-pv.w,q3.w, t.w))));
                    *(float4*)&Ls[R * STA + cb] = t;
                }
            }
            if (cb + 64 < Nn) {                                    // tail rows cb+64..79 (g<4)
                const int R = cb + 64 + l;
                if (R < Nn) {
                    float4 pv = *(const float4*)&Ls[R * STA + j0];
                    float4 t  = *(float4*)&Ls[R * STA + cb];
                    t.x = fmaf(-pv.x,q0.x, fmaf(-pv.y,q0.y, fmaf(-pv.z,q0.z, fmaf(-pv.w,q0.w, t.x))));
                    t.y = fmaf(-pv.x,q1.x, fmaf(-pv.y,q1.y, fmaf(-pv.z,q1.z, fmaf(-pv.w,q1.w, t.y))));
                    t.z = fmaf(-pv.x,q2.x, fmaf(-pv.y,q2.y, fmaf(-pv.z,q2.z, fmaf(-pv.w,q2.w, t.z))));
                    t.w = fmaf(-pv.x,q3.x, fmaf(-pv.y,q3.y, fmaf(-pv.z,q3.z, fmaf(-pv.w,q3.w, t.w))));
                    *(float4*)&Ls[R * STA + cb] = t;
                }
            }
        }
    }
    if (l == 0) ldp[w] = ldacc;
    __syncthreads();
    if (tid == 0) wsL[bk] = ldp[0]+ldp[1]+ldp[2]+ldp[3]+ldp[4]+ldp[5]+ldp[6]+ldp[7];

    // ---- A->B transition: zero strict-upper storage (W^T region); lower keeps L ----
    for (int i = tid; i < Nn * Nn; i += 512) {
        int r = i / Nn, c = i - Nn * r;
        if (c > r) Ls[r * STA + c] = 0.0f;
    }
    __syncthreads();

    // ---- Phase B: triangular inversion into storage-upper; L read from storage-lower --
    for (int p = 0; p < 20; ++p) {
        const int i0 = 4 * p;
        const bool b1a = (i0 + 3 >= l);
        const bool b2a = (l < 16) && (i0 + 3 >= r2);

        if (w == (p & 7)) {
            float m10 = Ls[(i0+1)*STA + i0];
            float m20 = Ls[(i0+2)*STA + i0];
            float m30 = Ls[(i0+3)*STA + i0];
            float m21 = Ls[(i0+2)*STA + i0+1];
            float m31 = Ls[(i0+3)*STA + i0+1];
            float m32 = Ls[(i0+3)*STA + i0+2];
            float4 iv = *(const float4*)&invd[i0];
            if (b1a) {
                float4 a = *(float4*)&Ls[l * STA + i0];
                if (l >= i0)   // virtual identity rows (diag block)
                    a = make_float4(l==i0?1.f:0.f, l==i0+1?1.f:0.f, l==i0+2?1.f:0.f, l==i0+3?1.f:0.f);
                float w0 = a.x * iv.x;
                float w1 = fmaf(-w0, m10, a.y) * iv.y;
                float w2 = fmaf(-w1, m21, fmaf(-w0, m20, a.z)) * iv.z;
                float w3 = fmaf(-w2, m32, fmaf(-w1, m31, fmaf(-w0, m30, a.w))) * iv.w;
                *(float4*)&Ls[l * STA + i0] = make_float4(w0, w1, w2, w3);
            }
            if (b2a) {
                float4 a = *(float4*)&Ls[r2 * STA + i0];
                if (r2 >= i0)
                    a = make_float4(r2==i0?1.f:0.f, r2==i0+1?1.f:0.f, r2==i0+2?1.f:0.f, r2==i0+3?1.f:0.f);
                float v0 = a.x * iv.x;
                float v1 = fmaf(-v0, m10, a.y) * iv.y;
                float v2 = fmaf(-v1, m21, fmaf(-v0, m20, a.z)) * iv.z;
                float v3 = fmaf(-v2, m32, fmaf(-v1, m31, fmaf(-v0, m30, a.w))) * iv.w;
                *(float4*)&Ls[r2 * STA + i0] = make_float4(v0, v1, v2, v3);
            }
        }
        __syncthreads();   // publish panel solve

        float4 wv = make_float4(0.f,0.f,0.f,0.f), vv = make_float4(0.f,0.f,0.f,0.f);
        if (b1a) wv = *(float4*)&Ls[l * STA + i0];
        if (b2a) vv = *(float4*)&Ls[r2 * STA + i0];
        if (b1a | b2a) {
            const int gs0 = p + 1;
            const int g0 = gs0 + ((w - gs0) & 7);
            for (int g = g0; g < 20; g += 8) {
                float4 q0 = *(const float4*)&Ls[(4*g+0) * STA + i0];  // L[4g+0][i0..i0+3]
                float4 q1 = *(const float4*)&Ls[(4*g+1) * STA + i0];
                float4 q2 = *(const float4*)&Ls[(4*g+2) * STA + i0];
                float4 q3 = *(const float4*)&Ls[(4*g+3) * STA + i0];
                if (b1a) {
                    float4 t = *(float4*)&Ls[l * STA + 4*g];
                    t.x = fmaf(-wv.x,q0.x, fmaf(-wv.y,q0.y, fmaf(-wv.z,q0.z, fmaf(-wv.w,q0.w, t.x))));
                    t.y = fmaf(-wv.x,q1.x, fmaf(-wv.y,q1.y, fmaf(-wv.z,q1.z, fmaf(-wv.w,q1.w, t.y))));
                    t.z = fmaf(-wv.x,q2.x, fmaf(-wv.y,q2.y, fmaf(-wv.z,q2.z, fmaf(-wv.w,q2.w, t.z))));
                    t.w = fmaf(-wv.x,q3.x, fmaf(-wv.y,q3.y, fmaf(-wv.z,q3.z, fmaf(-wv.w,q3.w, t.w))));
                    *(float4*)&Ls[l * STA + 4*g] = t;
                }
                if (b2a) {
                    float4 t = *(float4*)&Ls[r2 * STA + 4*g];
                    t.x = fmaf(-vv.x,q0.x, fmaf(-vv.y,q0.y, fmaf(-vv.z,q0.z, fmaf(-vv.w,q0.w, t.x))));
                    t.y = fmaf(-vv.x,q1.x, fmaf(-vv.y,q1.y, fmaf(-vv.z,q1.z, fmaf(-vv.w,q1.w, t.y))));
                    t.z = fmaf(-vv.x,q2.x, fmaf(-vv.y,q2.y, fmaf(-vv.z,q2.z, fmaf(-vv.w,q2.w, t.z))));
                    t.w = fmaf(-vv.x,q3.x, fmaf(-vv.y,q3.y, fmaf(-vv.z,q3.z, fmaf(-vv.w,q3.w, t.w))));
                    *(float4*)&Ls[r2 * STA + 4*g] = t;
                }
            }
        }
    }
    __syncthreads();

    // ---- Phase C: v = W*mu (mask c<=row since storage-lower holds L, not zeros) ----
    {
        float s1 = 0.f, s2 = 0.f;
        const int c0 = 10 * w;
        #pragma unroll 2
        for (int cc = 0; cc < 10; ++cc) {
            int c = c0 + cc;
            float mc = mus[c];
            float e1 = (c <= l)  ? Ls[c * STA + l]  : 0.f;   // W[l][c]
            s1 = fmaf(e1, mc, s1);
            if (l < 16) {
                float e2 = (c <= r2) ? Ls[c * STA + r2] : 0.f;
                s2 = fmaf(e2, mc, s2);
            }
        }
        vps[w * Nn + l] = s1;
        if (l < 16) vps[w * Nn + r2] = s2;
        __syncthreads();
        if (tid < Nn) {
            float acc = 0.f;
            #pragma unroll
            for (int ww = 0; ww < 8; ++ww) acc += vps[ww * Nn + tid];
            wsV[(size_t)bk * Nn + tid] = acc;
        }
    }

    // ---- Fragment pack (mask m>=kb+j; split 8 ways) ----
    const int n = l & 15, quad = l >> 4;
    uint4* ph = wsWh + (size_t)bk * 800;
    uint4* pq = wsWl + (size_t)bk * 800;
    for (int f = w; f < 10; f += 8) {
        int ks = f / 5, mt = f - 5 * ks;
        int m = 16 * mt + n, kb = 32 * ks + 8 * quad;
        unsigned hh[8], lo[8];
        #pragma unroll
        for (int j = 0; j < 8; ++j) {
            float wj = (m >= kb + j) ? Ls[(kb + j) * STA + m] : 0.f;   // = W[m][kb+j]
            unsigned short h = f2bf(wj);
            hh[j] = h; lo[j] = f2bf(wj - bf2f(h));
        }
        ph[f*64 + l] = make_uint4(hh[0]|(hh[1]<<16), hh[2]|(hh[3]<<16), hh[4]|(hh[5]<<16), hh[6]|(hh[7]<<16));
        pq[f*64 + l] = make_uint4(lo[0]|(lo[1]<<16), lo[2]|(lo[3]<<16), lo[4]|(lo[5]<<16), lo[6]|(lo[7]<<16));
    }
    if (w < 5) {
        int mt = w;
        if (quad < 2) {
            int m = 16 * mt + n, kb = 64 + 8 * quad;
            unsigned hh[8], lo[8];
            #pragma unroll
            for (int j = 0; j < 8; ++j) {
                float wj = (m >= kb + j) ? Ls[(kb + j) * STA + m] : 0.f;
                unsigned short h = f2bf(wj);
                hh[j] = h; lo[j] = f2bf(wj - bf2f(h));
            }
            ph[640 + mt*32 + l] = make_uint4(hh[0]|(hh[1]<<16), hh[2]|(hh[3]<<16), hh[4]|(hh[5]<<16), hh[6]|(hh[7]<<16));
            pq[640 + mt*32 + l] = make_uint4(lo[0]|(lo[1]<<16), lo[2]|(lo[3]<<16), lo[4]|(lo[5]<<16), lo[6]|(lo[7]<<16));
        }
    }

    // ---- Fused tail: x -> bf16 hi/lo B-fragments; coalesced 1KB/wave bursts ----
    if (doX) {
        const int wid = bk * 8 + w;            // 0..6143 wave-slots
        const int qd = l >> 4, n2 = l & 15;
        #pragma unroll
        for (int it = 0; it < 2; ++it) {
            int G = wid + 6144 * it;            // (b2, sg, ks) groups: 64*63*3 = 12096
            if (G >= 12096) break;
            int b2  = G / 189;
            int rem = G - b2 * 189;
            int sg  = rem / 3, ks = rem - 3 * sg;
            int s   = sg * 16 + n2;
            int k0  = 32 * ks + 8 * qd;
            float d[8] = {0.f,0.f,0.f,0.f,0.f,0.f,0.f,0.f};
            if (s < Ss) {
                const float* xp = x + ((size_t)b2 * Ss + s) * Nn + k0;
                float4 f0 = *(const float4*)xp;
                float4 f1 = *(const float4*)(xp + 4);
                d[0]=f0.x; d[1]=f0.y; d[2]=f0.z; d[3]=f0.w;
                d[4]=f1.x; d[5]=f1.y; d[6]=f1.z; d[7]=f1.w;
            }
            unsigned hh[8], lo[8];
            #pragma unroll
            for (int j = 0; j < 8; ++j) {
                unsigned short h = f2bf(d[j]);
                hh[j] = h; lo[j] = f2bf(d[j] - bf2f(h));
            }
            size_t slot = ((size_t)(b2 * 64 + sg) * 3 + ks) * 64 + l;
            Xh[slot] = make_uint4(hh[0]|(hh[1]<<16), hh[2]|(hh[3]<<16), hh[4]|(hh[5]<<16), hh[6]|(hh[7]<<16));
            Xl[slot] = make_uint4(lo[0]|(lo[1]<<16), lo[2]|(lo[3]<<16), lo[4]|(lo[5]<<16), lo[6]|(lo[7]<<16));
        }
    }
}

// ============ Kernel 2 (full tier, R11): 8-wave ll2 — 24 waves/CU to hide X-load latency
// Same math/layout as the validated 4-wave ll2; each wave now covers sg in [wv*8, wv*8+8)
// over 4 iterations of 2 sg. Total MFMA unchanged; per-wave chain halves; TLP doubles.
__global__ __launch_bounds__(512) void ll_kernel2(
    const uint4* __restrict__ Xh, const uint4* __restrict__ Xl,
    const uint4* __restrict__ wsWh, const uint4* __restrict__ wsWl,
    const float* __restrict__ wsV, const float* __restrict__ wsL,
    float* __restrict__ out)
{
    __shared__ uint4 WhL[960], WlL[960];   // [0..640): ks=0,1; [640..960): ks=2 expanded
    const int b = blockIdx.x;              // linear id = b + 64*k -> same-b blocks on one XCD
    const int k = blockIdx.y;
    const int bk = b * Kk + k;
    const int tid = threadIdx.x;
    const int wv = tid >> 6, lane = tid & 63;
    const int n = lane & 15, quad = lane >> 4;

    const uint4* gh = wsWh + (size_t)bk * 800;
    const uint4* gl = wsWl + (size_t)bk * 800;
    #pragma unroll
    for (int it = 0; it < 2; ++it) {
        int i = tid + 512 * it;
        if (i < 640) { WhL[i] = gh[i]; WlL[i] = gl[i]; }
    }
    if (tid < 320) {
        int mt = tid >> 6, ln = tid & 63, qd = (ln >> 4);
        uint4 vh = make_uint4(0,0,0,0), vl = make_uint4(0,0,0,0);
        if (qd < 2) { vh = gh[640 + mt*32 + ln]; vl = gl[640 + mt*32 + ln]; }
        WhL[640 + tid] = vh; WlL[640 + tid] = vl;
    }
    __syncthreads();

    const float ld = wsL[bk];
    f32x4 vf[5];
    #pragma unroll
    for (int mt = 0; mt < 5; ++mt)
        vf[mt] = *(const f32x4*)&wsV[(size_t)bk * Nn + 16*mt + 4*quad];

    for (int it = 0; it < 4; ++it) {
        const int sg0 = wv * 8 + it * 2;
        short8 bh[2][3], bl[2][3];
        #pragma unroll
        for (int t = 0; t < 2; ++t)
            #pragma unroll
            for (int ks = 0; ks < 3; ++ks) {
                size_t base = ((size_t)(b * 64 + sg0 + t) * 3 + ks) * 64 + lane;
                bh[t][ks] = __builtin_bit_cast(short8, Xh[base]);
                bl[t][ks] = __builtin_bit_cast(short8, Xl[base]);
            }

        f32x4 acc[2][5];
        #pragma unroll
        for (int t = 0; t < 2; ++t)
            #pragma unroll
            for (int mt = 0; mt < 5; ++mt) acc[t][mt] = (f32x4){0.f,0.f,0.f,0.f};

        #pragma unroll
        for (int ks = 0; ks < 3; ++ks) {
            #pragma unroll
            for (int mt = 0; mt < 5; ++mt) {
                const int fi = (ks < 2) ? (ks*5 + mt)*64 + lane : 640 + mt*64 + lane;
                short8 wh = __builtin_bit_cast(short8, WhL[fi]);
                short8 wl = __builtin_bit_cast(short8, WlL[fi]);
                #pragma unroll
                for (int t = 0; t < 2; ++t) {
                    acc[t][mt] = __builtin_amdgcn_mfma_f32_16x16x32_bf16(wh, bh[t][ks], acc[t][mt], 0, 0, 0);
                    acc[t][mt] = __builtin_amdgcn_mfma_f32_16x16x32_bf16(wl, bh[t][ks], acc[t][mt], 0, 0, 0);
                    acc[t][mt] = __builtin_amdgcn_mfma_f32_16x16x32_bf16(wh, bl[t][ks], acc[t][mt], 0, 0, 0);
                }
            }
        }

        #pragma unroll
        for (int t = 0; t < 2; ++t) {
            float q2 = 0.f;
            #pragma unroll
            for (int mt = 0; mt < 5; ++mt)
                #pragma unroll
                for (int r = 0; r < 4; ++r) {
                    float y = acc[t][mt][r] - vf[mt][r];
                    q2 = fmaf(y, y, q2);
                }
            q2 += __shfl_xor(q2, 16, 64);
            q2 += __shfl_xor(q2, 32, 64);
            int gs = (sg0 + t) * 16 + n;
            if (lane < 16 && gs < Ss)
                out[((size_t)b * Ss + gs) * Kk + k] = -0.5f * q2 - ld - CTERM;
        }
    }
}

// ============ Kernel 2 (mid tier): zero-LDS MFMA with in-kernel x conversion ===========
__global__ __launch_bounds__(256) void ll_kernel(
    const float* __restrict__ x,
    const uint4* __restrict__ wsWh, const uint4* __restrict__ wsWl,
    const float* __restrict__ wsV, const float* __restrict__ wsL,
    float* __restrict__ out)
{
    const int b    = blockIdx.x;
    const int st   = blockIdx.y;
    const int tid  = threadIdx.x;
    const int wv   = tid >> 6, lane = tid & 63;
    const int n    = lane & 15, quad = lane >> 4;
    const int sbase = st * 128 + wv * 32;

    short8 xh[2][3], xl[2][3];
    #pragma unroll
    for (int t = 0; t < 2; ++t) {
        int gs = sbase + 16 * t + n;
        #pragma unroll
        for (int ks = 0; ks < 3; ++ks) {
            int kb = 32 * ks + 8 * quad;
            float d[8] = {0.f,0.f,0.f,0.f,0.f,0.f,0.f,0.f};
            if (gs < Ss && kb < Nn) {
                const float* xp = x + ((size_t)b * Ss + gs) * Nn + kb;
                float4 f0 = *(const float4*)xp;
                float4 f1 = *(const float4*)(xp + 4);
                d[0]=f0.x; d[1]=f0.y; d[2]=f0.z; d[3]=f0.w;
                d[4]=f1.x; d[5]=f1.y; d[6]=f1.z; d[7]=f1.w;
            }
            short8 h, lo2;
            #pragma unroll
            for (int j = 0; j < 8; ++j) {
                unsigned short hv = f2bf(d[j]);
                h[j]   = (short)hv;
                lo2[j] = (short)f2bf(d[j] - bf2f(hv));
            }
            xh[t][ks] = h; xl[t][ks] = lo2;
        }
    }

    for (int k = 0; k < Kk; ++k) {
        const int bk = b * Kk + k;
        const uint4* ah_p = wsWh + (size_t)bk * 800;
        const uint4* al_p = wsWl + (size_t)bk * 800;

        f32x4 acc[2][5];
        #pragma unroll
        for (int t = 0; t < 2; ++t)
            #pragma unroll
            for (int mt = 0; mt < 5; ++mt) acc[t][mt] = (f32x4){0.f,0.f,0.f,0.f};

        #pragma unroll
        for (int ks = 0; ks < 3; ++ks) {
            short8 ah[5], al[5];
            if (ks < 2) {
                #pragma unroll
                for (int mt = 0; mt < 5; ++mt) {
                    ah[mt] = __builtin_bit_cast(short8, ah_p[(ks*5 + mt)*64 + lane]);
                    al[mt] = __builtin_bit_cast(short8, al_p[(ks*5 + mt)*64 + lane]);
                }
            } else {
                #pragma unroll
                for (int mt = 0; mt < 5; ++mt) {
                    uint4 zh = make_uint4(0,0,0,0), zl = make_uint4(0,0,0,0);
                    if (quad < 2) {
                        zh = ah_p[640 + mt*32 + lane];
                        zl = al_p[640 + mt*32 + lane];
                    }
                    ah[mt] = __builtin_bit_cast(short8, zh);
                    al[mt] = __builtin_bit_cast(short8, zl);
                }
            }
            #pragma unroll
            for (int mt = 0; mt < 5; ++mt)
                #pragma unroll
                for (int t = 0; t < 2; ++t) {
                    acc[t][mt] = __builtin_amdgcn_mfma_f32_16x16x32_bf16(ah[mt], xh[t][ks], acc[t][mt], 0, 0, 0);
                    acc[t][mt] = __builtin_amdgcn_mfma_f32_16x16x32_bf16(al[mt], xh[t][ks], acc[t][mt], 0, 0, 0);
                    acc[t][mt] = __builtin_amdgcn_mfma_f32_16x16x32_bf16(ah[mt], xl[t][ks], acc[t][mt], 0, 0, 0);
                }
        }

        float ld = wsL[bk];
        f32x4 vf[5];
        #pragma unroll
        for (int mt = 0; mt < 5; ++mt)
            vf[mt] = *(const f32x4*)&wsV[(size_t)bk * Nn + 16*mt + 4*quad];
        #pragma unroll
        for (int t = 0; t < 2; ++t) {
            float q2 = 0.f;
            #pragma unroll
            for (int mt = 0; mt < 5; ++mt)
                #pragma unroll
                for (int r = 0; r < 4; ++r) {
                    float y = acc[t][mt][r] - vf[mt][r];
                    q2 = fmaf(y, y, q2);
                }
            q2 += __shfl_xor(q2, 16, 64);
            q2 += __shfl_xor(q2, 32, 64);
            int gs = sbase + 16 * t + n;
            if (lane < 16 && gs < Ss)
                out[((size_t)b * Ss + gs) * Kk + k] = -0.5f * q2 - ld - CTERM;
        }
    }
}

// ============ Fallback (ws too small) ==================================================
#define ST1 81
__global__ __launch_bounds__(256) void mvn_ll_fallback(
    const float* __restrict__ x, const float* __restrict__ mu,
    const float* __restrict__ sigma, float* __restrict__ out)
{
    __shared__ float Ls[Nn * ST1];
    __shared__ float invd[Nn];
    __shared__ float mus[Nn];
    __shared__ float logdet_s;

    const int bk = blockIdx.x, b = bk / Kk, k = bk - b * Kk;
    const int tid = threadIdx.x, nt = blockDim.x;

    const float* sp = sigma + (size_t)bk * Nn * Nn;
    for (int t = tid; t < Nn * Nn; t += nt) Ls[(t / Nn) * ST1 + (t % Nn)] = sp[t];
    if (tid < Nn) mus[tid] = mu[(size_t)bk * Nn + tid];
    __syncthreads();
    if (tid < Nn) Ls[tid * ST1 + tid] += 1e-5f;
    __syncthreads();
    for (int j = 0; j < Nn; ++j) {
        if (tid == 0) {
            float d = sqrtf(Ls[j * ST1 + j]);
            Ls[j * ST1 + j] = d; invd[j] = 1.0f / d;
        }
        __syncthreads();
        const float inv = invd[j];
        for (int i = j + 1 + tid; i < Nn; i += nt) Ls[i * ST1 + j] *= inv;
        __syncthreads();
        for (int t = tid; t < Nn * Nn; t += nt) {
            int r = t / Nn, c = t % Nn;
            if (r > j && c > j && c <= r)
                Ls[r * ST1 + c] -= Ls[r * ST1 + j] * Ls[c * ST1 + j];
        }
        __syncthreads();
    }
    if (tid == 0) {
        float a = 0.f; for (int j = 0; j < Nn; ++j) a += logf(Ls[j * ST1 + j]);
        logdet_s = a;
    }
    __syncthreads();
    const float ld = logdet_s;
    for (int s = tid; s < Ss; s += nt) {
        const float4* xp = (const float4*)(x + ((size_t)b * Ss + s) * Nn);
        float a[Nn];
        #pragma unroll
        for (int q = 0; q < Nn / 4; ++q) {
            float4 v = xp[q];
            a[4*q+0] = v.x - mus[4*q+0]; a[4*q+1] = v.y - mus[4*q+1];
            a[4*q+2] = v.z - mus[4*q+2]; a[4*q+3] = v.w - mus[4*q+3];
        }
        #pragma unroll
        for (int i = 0; i < Nn; ++i) {
            float t = a[i];
            #pragma unroll
            for (int j = 0; j < i; ++j) t = fmaf(-Ls[i * ST1 + j], a[j], t);
            a[i] = t * invd[i];
        }
        float quad = 0.f;
        #pragma unroll
        for (int i = 0; i < Nn; ++i) quad = fmaf(a[i], a[i], quad);
        out[((size_t)b * Ss + s) * Kk + k] = -0.5f * quad - ld - CTERM;
    }
}

extern "C" void kernel_launch(void* const* d_in, const int* in_sizes, int n_in,
                              void* d_out, int out_size, void* d_ws, size_t ws_size,
                              hipStream_t stream) {
    const float* x     = (const float*)d_in[0];
    const float* mu    = (const float*)d_in[1];
    const float* sigma = (const float*)d_in[2];
    float* out = (float*)d_out;

    const size_t nBK   = (size_t)Bb * Kk;            // 768
    const size_t nWu4  = nBK * 800;                  // W frag uint4s per array
    const size_t nXu4  = (size_t)Bb * 64 * 3 * 64;   // 786432 x-frag uint4s per array
    const size_t need_mid  = nWu4 * 16 * 2 + nBK * Nn * 4 + nBK * 4;
    const size_t need_full = need_mid + nXu4 * 16 * 2;

    if (ws_size >= need_full) {
        uint4* wsWh = (uint4*)d_ws;
        uint4* wsWl = wsWh + nWu4;
        uint4* Xh   = wsWl + nWu4;
        uint4* Xl   = Xh + nXu4;
        float* wsV  = (float*)(Xl + nXu4);
        float* wsL  = wsV + nBK * Nn;
        prep_kernel<<<dim3(Bb * Kk), dim3(512), 0, stream>>>(
            sigma, mu, x, wsWh, wsWl, wsV, wsL, Xh, Xl, 1);
        ll_kernel2<<<dim3(Bb, Kk), dim3(512), 0, stream>>>(Xh, Xl, wsWh, wsWl, wsV, wsL, out);
    } else if (ws_size >= need_mid) {
        uint4* wsWh = (uint4*)d_ws;
        uint4* wsWl = wsWh + nWu4;
        float* wsV  = (float*)(wsWl + nWu4);
        float* wsL  = wsV + nBK * Nn;
        prep_kernel<<<dim3(Bb * Kk), dim3(512), 0, stream>>>(
            sigma, mu, x, wsWh, wsWl, wsV, wsL, (uint4*)nullptr, (uint4*)nullptr, 0);
        ll_kernel<<<dim3(Bb, 8), dim3(256), 0, stream>>>(x, wsWh, wsWl, wsV, wsL, out);
    } else {
        mvn_ll_fallback<<<dim3(Bb * Kk), dim3(256), 0, stream>>>(x, mu, sigma, out);
    }
}

// Round 13
// 149.340 us; speedup vs baseline: 2.2459x; 1.0566x over previous
//
#include <hip/hip_runtime.h>

#define Bb 64
#define Ss 1000
#define Kk 12
#define Nn 80
#define CTERM 73.51508265637381f   // 0.5 * 80 * log(2*pi)
#define STA 84                     // fp32 LDS stride (336 B, 16B-aligned)

typedef __attribute__((ext_vector_type(8))) short short8;
typedef __attribute__((ext_vector_type(4))) float f32x4;

static __device__ __forceinline__ unsigned short f2bf(float f) {
    unsigned u = __builtin_bit_cast(unsigned, f);
    unsigned r = u + 0x7FFFu + ((u >> 16) & 1u);   // round-to-nearest-even
    return (unsigned short)(r >> 16);
}
static __device__ __forceinline__ float bf2f(unsigned short h) {
    unsigned u = ((unsigned)h) << 16;
    return __builtin_bit_cast(float, u);
}

// ============ Kernel 1 (R13): R7 8-wave prep; x-tail writes Xh ONLY (bf16 x) ===========
// Error budget: sigma = A A^T/N + I => lambda_min >= 1 => ||W row||_2 <= 1, so bf16 x
// contributes delta_ll <~ 0.1 vs threshold 4.08. Xl pipeline deleted.
__global__ __launch_bounds__(512, 6) void prep_kernel(
    const float* __restrict__ sigma, const float* __restrict__ mu,
    const float* __restrict__ x,
    uint4* __restrict__ wsWh, uint4* __restrict__ wsWl,   // [768][800] uint4
    float* __restrict__ wsV, float* __restrict__ wsL,
    uint4* __restrict__ Xh, int doX)
{
    __shared__ float Ls[Nn * STA];   // A: working matrix; B: lower=L, upper=W^T
    __shared__ float invd[Nn];
    __shared__ float mus[Nn];
    __shared__ float ldp[8];
    __shared__ float vps[8 * Nn];    // Phase C partial v

    const int bk  = blockIdx.x;
    const int tid = threadIdx.x;
    const int w   = tid >> 6;        // 0..7
    const int l   = tid & 63;
    const int r2  = l + 64;

    // ---- stage sigma: lower + diag-block only (c4 <= r+3) ----
    const float4* sp4 = (const float4*)(sigma + (size_t)bk * Nn * Nn);
    #pragma unroll
    for (int it = 0; it < 4; ++it) {
        int ci = tid + 512 * it;
        if (ci < 1600) {
            int r = ci / 20, c4 = 4 * (ci - 20 * r);
            if (c4 <= r + 3) {
                float4 v = sp4[ci];
                *(float4*)&Ls[r * STA + c4] = v;
            }
        }
    }
    if (tid < Nn) mus[tid] = mu[(size_t)bk * Nn + tid];
    __syncthreads();
    if (tid < Nn) Ls[tid * STA + tid] += 1e-5f;
    __syncthreads();

    // ---- Phase A: blocked Cholesky; master = wave (p&7); 1 barrier/panel ----
    float ldacc = 0.0f;
    for (int p = 0; p < 20; ++p) {
        const int j0 = 4 * p;
        const bool a1 = (l >= j0);
        const bool a2 = (l < 16) && (r2 >= j0);

        if (w == (p & 7)) {
            float B00 = Ls[j0*STA+j0];
            float B10 = Ls[(j0+1)*STA+j0], B11 = Ls[(j0+1)*STA+j0+1];
            float B20 = Ls[(j0+2)*STA+j0], B21 = Ls[(j0+2)*STA+j0+1], B22 = Ls[(j0+2)*STA+j0+2];
            float B30 = Ls[(j0+3)*STA+j0], B31 = Ls[(j0+3)*STA+j0+1], B32 = Ls[(j0+3)*STA+j0+2], B33 = Ls[(j0+3)*STA+j0+3];
            float rv0 = rsqrtf(B00);
            float l10 = B10*rv0, l20 = B20*rv0, l30 = B30*rv0;
            float t11 = fmaf(-l10,l10,B11);                    float rv1 = rsqrtf(t11);
            float l21 = fmaf(-l20,l10,B21)*rv1;
            float l31 = fmaf(-l30,l10,B31)*rv1;
            float t22 = fmaf(-l21,l21,fmaf(-l20,l20,B22));     float rv2 = rsqrtf(t22);
            float l32 = fmaf(-l31,l21,fmaf(-l30,l20,B32))*rv2;
            float t33 = fmaf(-l32,l32,fmaf(-l31,l31,fmaf(-l30,l30,B33)));
            float rv3 = rsqrtf(t33);
            ldacc += 0.5f * (logf(B00) + logf(t11) + logf(t22) + logf(t33));
            if (l == 0) { invd[j0]=rv0; invd[j0+1]=rv1; invd[j0+2]=rv2; invd[j0+3]=rv3; }

            if (a1) {
                float4 a = *(float4*)&Ls[l * STA + j0];
                float b0 = a.x * rv0;
                float b1 = fmaf(-l10, b0, a.y) * rv1;
                float b2 = fmaf(-l21, b1, fmaf(-l20, b0, a.z)) * rv2;
                float b3 = fmaf(-l32, b2, fmaf(-l31, b1, fmaf(-l30, b0, a.w))) * rv3;
                *(float4*)&Ls[l * STA + j0] = make_float4(b0, b1, b2, b3);
            }
            if (a2) {
                float4 a = *(float4*)&Ls[r2 * STA + j0];
                float c0 = a.x * rv0;
                float c1 = fmaf(-l10, c0, a.y) * rv1;
                float c2 = fmaf(-l21, c1, fmaf(-l20, c0, a.z)) * rv2;
                float c3 = fmaf(-l32, c2, fmaf(-l31, c1, fmaf(-l30, c0, a.w))) * rv3;
                *(float4*)&Ls[r2 * STA + j0] = make_float4(c0, c1, c2, c3);
            }
        }
        __syncthreads();   // publish panel solve; the ONLY barrier this panel

        // lower-only update of owned groups (g ≡ w mod 8, g > p); lane l -> row 4g+l
        const int gs0 = p + 1;
        const int g0 = gs0 + ((w - gs0) & 7);
        #pragma unroll 2
        for (int g = g0; g < 20; g += 8) {
            const int cb = 4 * g;
            float4 q0 = *(const float4*)&Ls[(cb+0) * STA + j0];   // L[cb+c][j0..j0+3]
            float4 q1 = *(const float4*)&Ls[(cb+1) * STA + j0];
            float4 q2 = *(const float4*)&Ls[(cb+2) * STA + j0];
            float4 q3 = *(const float4*)&Ls[(cb+3) * STA + j0];
            {
                const int R = cb + l;                              // rows cb..cb+63
                if (R < Nn) {
                    float4 pv = *(const float4*)&Ls[R * STA + j0];
                    float4 t  = *(float4*)&Ls[R * STA + cb];
                    t.x = fmaf(-pv.x,q0.x, fmaf(-pv.y,q0.y, fmaf(-pv.z,q0.z, fmaf(-pv.w,q0.w, t.x))));
                    t.y = fmaf(-pv.x,q1.x, fmaf(-pv.y,q1.y, fmaf(-pv.z,q1.z, fmaf(-pv.w,q1.w, t.y))));
                    t.z = fmaf(-pv.x,q2.x, fmaf(-pv.y,q2.y, fmaf(-pv.z,q2.z, fmaf(-pv.w,q2.w, t.z))));
                    t.w = fmaf(-pv.x,q3.x, fmaf(-pv.y,q3.y, fmaf(-pv.z,q3.z, fmaf(-pv.w,q3.w, t.w))));
                    *(float4*)&Ls[R * STA + cb] = t;
                }
            }
            if (cb + 64 < Nn) {                                    // tail rows cb+64..79 (g<4)
                const int R = cb + 64 + l;
                if (R < Nn) {
                    float4 pv = *(const float4*)&Ls[R * STA + j0];
                    float4 t  = *(float4*)&Ls[R * STA + cb];
                    t.x = fmaf(-pv.x,q0.x, fmaf(-pv.y,q0.y, fmaf(-pv.z,q0.z, fmaf(-pv.w,q0.w, t.x))));
                    t.y = fmaf(-pv.x,q1.x, fmaf(-pv.y,q1.y, fmaf(-pv.z,q1.z, fmaf(-pv.w,q1.w, t.y))));
                    t.z = fmaf(-pv.x,q2.x, fmaf(-pv.y,q2.y, fmaf(-pv.z,q2.z, fmaf(-pv.w,q2.w, t.z))));
                    t.w = fmaf(-pv.x,q3.x, fmaf(-pv.y,q3.y, fmaf(-pv.z,q3.z, fmaf(-pv.w,q3.w, t.w))));
                    *(float4*)&Ls[R * STA + cb] = t;
                }
            }
        }
    }
    if (l == 0) ldp[w] = ldacc;
    __syncthreads();
    if (tid == 0) wsL[bk] = ldp[0]+ldp[1]+ldp[2]+ldp[3]+ldp[4]+ldp[5]+ldp[6]+ldp[7];

    // ---- A->B transition: zero strict-upper storage (W^T region); lower keeps L ----
    for (int i = tid; i < Nn * Nn; i += 512) {
        int r = i / Nn, c = i - Nn * r;
        if (c > r) Ls[r * STA + c] = 0.0f;
    }
    __syncthreads();

    // ---- Phase B: triangular inversion into storage-upper; L read from storage-lower --
    for (int p = 0; p < 20; ++p) {
        const int i0 = 4 * p;
        const bool b1a = (i0 + 3 >= l);
        const bool b2a = (l < 16) && (i0 + 3 >= r2);

        if (w == (p & 7)) {
            float m10 = Ls[(i0+1)*STA + i0];
            float m20 = Ls[(i0+2)*STA + i0];
            float m30 = Ls[(i0+3)*STA + i0];
            float m21 = Ls[(i0+2)*STA + i0+1];
            float m31 = Ls[(i0+3)*STA + i0+1];
            float m32 = Ls[(i0+3)*STA + i0+2];
            float4 iv = *(const float4*)&invd[i0];
            if (b1a) {
                float4 a = *(float4*)&Ls[l * STA + i0];
                if (l >= i0)   // virtual identity rows (diag block)
                    a = make_float4(l==i0?1.f:0.f, l==i0+1?1.f:0.f, l==i0+2?1.f:0.f, l==i0+3?1.f:0.f);
                float w0 = a.x * iv.x;
                float w1 = fmaf(-w0, m10, a.y) * iv.y;
                float w2 = fmaf(-w1, m21, fmaf(-w0, m20, a.z)) * iv.z;
                float w3 = fmaf(-w2, m32, fmaf(-w1, m31, fmaf(-w0, m30, a.w))) * iv.w;
                *(float4*)&Ls[l * STA + i0] = make_float4(w0, w1, w2, w3);
            }
            if (b2a) {
                float4 a = *(float4*)&Ls[r2 * STA + i0];
                if (r2 >= i0)
                    a = make_float4(r2==i0?1.f:0.f, r2==i0+1?1.f:0.f, r2==i0+2?1.f:0.f, r2==i0+3?1.f:0.f);
                float v0 = a.x * iv.x;
                float v1 = fmaf(-v0, m10, a.y) * iv.y;
                float v2 = fmaf(-v1, m21, fmaf(-v0, m20, a.z)) * iv.z;
                float v3 = fmaf(-v2, m32, fmaf(-v1, m31, fmaf(-v0, m30, a.w))) * iv.w;
                *(float4*)&Ls[r2 * STA + i0] = make_float4(v0, v1, v2, v3);
            }
        }
        __syncthreads();   // publish panel solve

        float4 wv = make_float4(0.f,0.f,0.f,0.f), vv = make_float4(0.f,0.f,0.f,0.f);
        if (b1a) wv = *(float4*)&Ls[l * STA + i0];
        if (b2a) vv = *(float4*)&Ls[r2 * STA + i0];
        if (b1a | b2a) {
            const int gs0 = p + 1;
            const int g0 = gs0 + ((w - gs0) & 7);
            for (int g = g0; g < 20; g += 8) {
                float4 q0 = *(const float4*)&Ls[(4*g+0) * STA + i0];  // L[4g+0][i0..i0+3]
                float4 q1 = *(const float4*)&Ls[(4*g+1) * STA + i0];
                float4 q2 = *(const float4*)&Ls[(4*g+2) * STA + i0];
                float4 q3 = *(const float4*)&Ls[(4*g+3) * STA + i0];
                if (b1a) {
                    float4 t = *(float4*)&Ls[l * STA + 4*g];
                    t.x = fmaf(-wv.x,q0.x, fmaf(-wv.y,q0.y, fmaf(-wv.z,q0.z, fmaf(-wv.w,q0.w, t.x))));
                    t.y = fmaf(-wv.x,q1.x, fmaf(-wv.y,q1.y, fmaf(-wv.z,q1.z, fmaf(-wv.w,q1.w, t.y))));
                    t.z = fmaf(-wv.x,q2.x, fmaf(-wv.y,q2.y, fmaf(-wv.z,q2.z, fmaf(-wv.w,q2.w, t.z))));
                    t.w = fmaf(-wv.x,q3.x, fmaf(-wv.y,q3.y, fmaf(-wv.z,q3.z, fmaf(-wv.w,q3.w, t.w))));
                    *(float4*)&Ls[l * STA + 4*g] = t;
                }
                if (b2a) {
                    float4 t = *(float4*)&Ls[r2 * STA + 4*g];
                    t.x = fmaf(-vv.x,q0.x, fmaf(-vv.y,q0.y, fmaf(-vv.z,q0.z, fmaf(-vv.w,q0.w, t.x))));
                    t.y = fmaf(-vv.x,q1.x, fmaf(-vv.y,q1.y, fmaf(-vv.z,q1.z, fmaf(-vv.w,q1.w, t.y))));
                    t.z = fmaf(-vv.x,q2.x, fmaf(-vv.y,q2.y, fmaf(-vv.z,q2.z, fmaf(-vv.w,q2.w, t.z))));
                    t.w = fmaf(-vv.x,q3.x, fmaf(-vv.y,q3.y, fmaf(-vv.z,q3.z, fmaf(-vv.w,q3.w, t.w))));
                    *(float4*)&Ls[r2 * STA + 4*g] = t;
                }
            }
        }
    }
    __syncthreads();

    // ---- Phase C: v = W*mu (mask c<=row since storage-lower holds L, not zeros) ----
    {
        float s1 = 0.f, s2 = 0.f;
        const int c0 = 10 * w;
        #pragma unroll 2
        for (int cc = 0; cc < 10; ++cc) {
            int c = c0 + cc;
            float mc = mus[c];
            float e1 = (c <= l)  ? Ls[c * STA + l]  : 0.f;   // W[l][c]
            s1 = fmaf(e1, mc, s1);
            if (l < 16) {
                float e2 = (c <= r2) ? Ls[c * STA + r2] : 0.f;
                s2 = fmaf(e2, mc, s2);
            }
        }
        vps[w * Nn + l] = s1;
        if (l < 16) vps[w * Nn + r2] = s2;
        __syncthreads();
        if (tid < Nn) {
            float acc = 0.f;
            #pragma unroll
            for (int ww = 0; ww < 8; ++ww) acc += vps[ww * Nn + tid];
            wsV[(size_t)bk * Nn + tid] = acc;
        }
    }

    // ---- Fragment pack (mask m>=kb+j; split 8 ways) — W keeps hi+lo ----
    const int n = l & 15, quad = l >> 4;
    uint4* ph = wsWh + (size_t)bk * 800;
    uint4* pq = wsWl + (size_t)bk * 800;
    for (int f = w; f < 10; f += 8) {
        int ks = f / 5, mt = f - 5 * ks;
        int m = 16 * mt + n, kb = 32 * ks + 8 * quad;
        unsigned hh[8], lo[8];
        #pragma unroll
        for (int j = 0; j < 8; ++j) {
            float wj = (m >= kb + j) ? Ls[(kb + j) * STA + m] : 0.f;   // = W[m][kb+j]
            unsigned short h = f2bf(wj);
            hh[j] = h; lo[j] = f2bf(wj - bf2f(h));
        }
        ph[f*64 + l] = make_uint4(hh[0]|(hh[1]<<16), hh[2]|(hh[3]<<16), hh[4]|(hh[5]<<16), hh[6]|(hh[7]<<16));
        pq[f*64 + l] = make_uint4(lo[0]|(lo[1]<<16), lo[2]|(lo[3]<<16), lo[4]|(lo[5]<<16), lo[6]|(lo[7]<<16));
    }
    if (w < 5) {
        int mt = w;
        if (quad < 2) {
            int m = 16 * mt + n, kb = 64 + 8 * quad;
            unsigned hh[8], lo[8];
            #pragma unroll
            for (int j = 0; j < 8; ++j) {
                float wj = (m >= kb + j) ? Ls[(kb + j) * STA + m] : 0.f;
                unsigned short h = f2bf(wj);
                hh[j] = h; lo[j] = f2bf(wj - bf2f(h));
            }
            ph[640 + mt*32 + l] = make_uint4(hh[0]|(hh[1]<<16), hh[2]|(hh[3]<<16), hh[4]|(hh[5]<<16), hh[6]|(hh[7]<<16));
            pq[640 + mt*32 + l] = make_uint4(lo[0]|(lo[1]<<16), lo[2]|(lo[3]<<16), lo[4]|(lo[5]<<16), lo[6]|(lo[7]<<16));
        }
    }

    // ---- Fused tail: x -> bf16 HI-ONLY B-fragments; coalesced 1KB/wave bursts ----
    if (doX) {
        const int wid = bk * 8 + w;            // 0..6143 wave-slots
        const int qd = l >> 4, n2 = l & 15;
        #pragma unroll
        for (int it = 0; it < 2; ++it) {
            int G = wid + 6144 * it;            // (b2, sg, ks) groups: 64*63*3 = 12096
            if (G >= 12096) break;
            int b2  = G / 189;
            int rem = G - b2 * 189;
            int sg  = rem / 3, ks = rem - 3 * sg;
            int s   = sg * 16 + n2;
            int k0  = 32 * ks + 8 * qd;
            float d[8] = {0.f,0.f,0.f,0.f,0.f,0.f,0.f,0.f};
            if (s < Ss) {
                const float* xp = x + ((size_t)b2 * Ss + s) * Nn + k0;
                float4 f0 = *(const float4*)xp;
                float4 f1 = *(const float4*)(xp + 4);
                d[0]=f0.x; d[1]=f0.y; d[2]=f0.z; d[3]=f0.w;
                d[4]=f1.x; d[5]=f1.y; d[6]=f1.z; d[7]=f1.w;
            }
            unsigned hh[8];
            #pragma unroll
            for (int j = 0; j < 8; ++j) hh[j] = f2bf(d[j]);
            size_t slot = ((size_t)(b2 * 64 + sg) * 3 + ks) * 64 + l;
            Xh[slot] = make_uint4(hh[0]|(hh[1]<<16), hh[2]|(hh[3]<<16), hh[4]|(hh[5]<<16), hh[6]|(hh[7]<<16));
        }
    }
}

// ============ Kernel 2 (full tier, R13): 8-wave ll2, 2-term MFMA (W hi+lo, X hi) =======
__global__ __launch_bounds__(512) void ll_kernel2(
    const uint4* __restrict__ Xh,
    const uint4* __restrict__ wsWh, const uint4* __restrict__ wsWl,
    const float* __restrict__ wsV, const float* __restrict__ wsL,
    float* __restrict__ out)
{
    __shared__ uint4 WhL[960], WlL[960];   // [0..640): ks=0,1; [640..960): ks=2 expanded
    const int b = blockIdx.x;
    const int k = blockIdx.y;
    const int bk = b * Kk + k;
    const int tid = threadIdx.x;
    const int wv = tid >> 6, lane = tid & 63;
    const int n = lane & 15, quad = lane >> 4;

    const uint4* gh = wsWh + (size_t)bk * 800;
    const uint4* gl = wsWl + (size_t)bk * 800;
    #pragma unroll
    for (int it = 0; it < 2; ++it) {
        int i = tid + 512 * it;
        if (i < 640) { WhL[i] = gh[i]; WlL[i] = gl[i]; }
    }
    if (tid < 320) {
        int mt = tid >> 6, ln = tid & 63, qd = (ln >> 4);
        uint4 vh = make_uint4(0,0,0,0), vl = make_uint4(0,0,0,0);
        if (qd < 2) { vh = gh[640 + mt*32 + ln]; vl = gl[640 + mt*32 + ln]; }
        WhL[640 + tid] = vh; WlL[640 + tid] = vl;
    }
    __syncthreads();

    const float ld = wsL[bk];
    f32x4 vf[5];
    #pragma unroll
    for (int mt = 0; mt < 5; ++mt)
        vf[mt] = *(const f32x4*)&wsV[(size_t)bk * Nn + 16*mt + 4*quad];

    for (int it = 0; it < 4; ++it) {
        const int sg0 = wv * 8 + it * 2;
        short8 bh[2][3];
        #pragma unroll
        for (int t = 0; t < 2; ++t)
            #pragma unroll
            for (int ks = 0; ks < 3; ++ks) {
                size_t base = ((size_t)(b * 64 + sg0 + t) * 3 + ks) * 64 + lane;
                bh[t][ks] = __builtin_bit_cast(short8, Xh[base]);
            }

        f32x4 acc[2][5];
        #pragma unroll
        for (int t = 0; t < 2; ++t)
            #pragma unroll
            for (int mt = 0; mt < 5; ++mt) acc[t][mt] = (f32x4){0.f,0.f,0.f,0.f};

        #pragma unroll
        for (int ks = 0; ks < 3; ++ks) {
            #pragma unroll
            for (int mt = 0; mt < 5; ++mt) {
                const int fi = (ks < 2) ? (ks*5 + mt)*64 + lane : 640 + mt*64 + lane;
                short8 wh = __builtin_bit_cast(short8, WhL[fi]);
                short8 wl = __builtin_bit_cast(short8, WlL[fi]);
                #pragma unroll
                for (int t = 0; t < 2; ++t) {
                    acc[t][mt] = __builtin_amdgcn_mfma_f32_16x16x32_bf16(wh, bh[t][ks], acc[t][mt], 0, 0, 0);
                    acc[t][mt] = __builtin_amdgcn_mfma_f32_16x16x32_bf16(wl, bh[t][ks], acc[t][mt], 0, 0, 0);
                }
            }
        }

        #pragma unroll
        for (int t = 0; t < 2; ++t) {
            float q2 = 0.f;
            #pragma unroll
            for (int mt = 0; mt < 5; ++mt)
                #pragma unroll
                for (int r = 0; r < 4; ++r) {
                    float y = acc[t][mt][r] - vf[mt][r];
                    q2 = fmaf(y, y, q2);
                }
            q2 += __shfl_xor(q2, 16, 64);
            q2 += __shfl_xor(q2, 32, 64);
            int gs = (sg0 + t) * 16 + n;
            if (lane < 16 && gs < Ss)
                out[((size_t)b * Ss + gs) * Kk + k] = -0.5f * q2 - ld - CTERM;
        }
    }
}

// ============ Kernel 2 (mid tier): zero-LDS MFMA with in-kernel x conversion ===========
__global__ __launch_bounds__(256) void ll_kernel(
    const float* __restrict__ x,
    const uint4* __restrict__ wsWh, const uint4* __restrict__ wsWl,
    const float* __restrict__ wsV, const float* __restrict__ wsL,
    float* __restrict__ out)
{
    const int b    = blockIdx.x;
    const int st   = blockIdx.y;
    const int tid  = threadIdx.x;
    const int wv   = tid >> 6, lane = tid & 63;
    const int n    = lane & 15, quad = lane >> 4;
    const int sbase = st * 128 + wv * 32;

    short8 xh[2][3];
    #pragma unroll
    for (int t = 0; t < 2; ++t) {
        int gs = sbase + 16 * t + n;
        #pragma unroll
        for (int ks = 0; ks < 3; ++ks) {
            int kb = 32 * ks + 8 * quad;
            float d[8] = {0.f,0.f,0.f,0.f,0.f,0.f,0.f,0.f};
            if (gs < Ss && kb < Nn) {
                const float* xp = x + ((size_t)b * Ss + gs) * Nn + kb;
                float4 f0 = *(const float4*)xp;
                float4 f1 = *(const float4*)(xp + 4);
                d[0]=f0.x; d[1]=f0.y; d[2]=f0.z; d[3]=f0.w;
                d[4]=f1.x; d[5]=f1.y; d[6]=f1.z; d[7]=f1.w;
            }
            short8 h;
            #pragma unroll
            for (int j = 0; j < 8; ++j) h[j] = (short)f2bf(d[j]);
            xh[t][ks] = h;
        }
    }

    for (int k = 0; k < Kk; ++k) {
        const int bk = b * Kk + k;
        const uint4* ah_p = wsWh + (size_t)bk * 800;
        const uint4* al_p = wsWl + (size_t)bk * 800;

        f32x4 acc[2][5];
        #pragma unroll
        for (int t = 0; t < 2; ++t)
            #pragma unroll
            for (int mt = 0; mt < 5; ++mt) acc[t][mt] = (f32x4){0.f,0.f,0.f,0.f};

        #pragma unroll
        for (int ks = 0; ks < 3; ++ks) {
            short8 ah[5], al[5];
            if (ks < 2) {
                #pragma unroll
                for (int mt = 0; mt < 5; ++mt) {
                    ah[mt] = __builtin_bit_cast(short8, ah_p[(ks*5 + mt)*64 + lane]);
                    al[mt] = __builtin_bit_cast(short8, al_p[(ks*5 + mt)*64 + lane]);
                }
            } else {
                #pragma unroll
                for (int mt = 0; mt < 5; ++mt) {
                    uint4 zh = make_uint4(0,0,0,0), zl = make_uint4(0,0,0,0);
                    if (quad < 2) {
                        zh = ah_p[640 + mt*32 + lane];
                        zl = al_p[640 + mt*32 + lane];
                    }
                    ah[mt] = __builtin_bit_cast(short8, zh);
                    al[mt] = __builtin_bit_cast(short8, zl);
                }
            }
            #pragma unroll
            for (int mt = 0; mt < 5; ++mt)
                #pragma unroll
                for (int t = 0; t < 2; ++t) {
                    acc[t][mt] = __builtin_amdgcn_mfma_f32_16x16x32_bf16(ah[mt], xh[t][ks], acc[t][mt], 0, 0, 0);
                    acc[t][mt] = __builtin_amdgcn_mfma_f32_16x16x32_bf16(al[mt], xh[t][ks], acc[t][mt], 0, 0, 0);
                }
        }

        float ld = wsL[bk];
        f32x4 vf[5];
        #pragma unroll
        for (int mt = 0; mt < 5; ++mt)
            vf[mt] = *(const f32x4*)&wsV[(size_t)bk * Nn + 16*mt + 4*quad];
        #pragma unroll
        for (int t = 0; t < 2; ++t) {
            float q2 = 0.f;
            #pragma unroll
            for (int mt = 0; mt < 5; ++mt)
                #pragma unroll
                for (int r = 0; r < 4; ++r) {
                    float y = acc[t][mt][r] - vf[mt][r];
                    q2 = fmaf(y, y, q2);
                }
            q2 += __shfl_xor(q2, 16, 64);
            q2 += __shfl_xor(q2, 32, 64);
            int gs = sbase + 16 * t + n;
            if (lane < 16 && gs < Ss)
                out[((size_t)b * Ss + gs) * Kk + k] = -0.5f * q2 - ld - CTERM;
        }
    }
}

// ============ Fallback (ws too small) ==================================================
#define ST1 81
__global__ __launch_bounds__(256) void mvn_ll_fallback(
    const float* __restrict__ x, const float* __restrict__ mu,
    const float* __restrict__ sigma, float* __restrict__ out)
{
    __shared__ float Ls[Nn * ST1];
    __shared__ float invd[Nn];
    __shared__ float mus[Nn];
    __shared__ float logdet_s;

    const int bk = blockIdx.x, b = bk / Kk, k = bk - b * Kk;
    const int tid = threadIdx.x, nt = blockDim.x;

    const float* sp = sigma + (size_t)bk * Nn * Nn;
    for (int t = tid; t < Nn * Nn; t += nt) Ls[(t / Nn) * ST1 + (t % Nn)] = sp[t];
    if (tid < Nn) mus[tid] = mu[(size_t)bk * Nn + tid];
    __syncthreads();
    if (tid < Nn) Ls[tid * ST1 + tid] += 1e-5f;
    __syncthreads();
    for (int j = 0; j < Nn; ++j) {
        if (tid == 0) {
            float d = sqrtf(Ls[j * ST1 + j]);
            Ls[j * ST1 + j] = d; invd[j] = 1.0f / d;
        }
        __syncthreads();
        const float inv = invd[j];
        for (int i = j + 1 + tid; i < Nn; i += nt) Ls[i * ST1 + j] *= inv;
        __syncthreads();
        for (int t = tid; t < Nn * Nn; t += nt) {
            int r = t / Nn, c = t % Nn;
            if (r > j && c > j && c <= r)
                Ls[r * ST1 + c] -= Ls[r * ST1 + j] * Ls[c * ST1 + j];
        }
        __syncthreads();
    }
    if (tid == 0) {
        float a = 0.f; for (int j = 0; j < Nn; ++j) a += logf(Ls[j * ST1 + j]);
        logdet_s = a;
    }
    __syncthreads();
    const float ld = logdet_s;
    for (int s = tid; s < Ss; s += nt) {
        const float4* xp = (const float4*)(x + ((size_t)b * Ss + s) * Nn);
        float a[Nn];
        #pragma unroll
        for (int q = 0; q < Nn / 4; ++q) {
            float4 v = xp[q];
            a[4*q+0] = v.x - mus[4*q+0]; a[4*q+1] = v.y - mus[4*q+1];
            a[4*q+2] = v.z - mus[4*q+2]; a[4*q+3] = v.w - mus[4*q+3];
        }
        #pragma unroll
        for (int i = 0; i < Nn; ++i) {
            float t = a[i];
            #pragma unroll
            for (int j = 0; j < i; ++j) t = fmaf(-Ls[i * ST1 + j], a[j], t);
            a[i] = t * invd[i];
        }
        float quad = 0.f;
        #pragma unroll
        for (int i = 0; i < Nn; ++i) quad = fmaf(a[i], a[i], quad);
        out[((size_t)b * Ss + s) * Kk + k] = -0.5f * quad - ld - CTERM;
    }
}

extern "C" void kernel_launch(void* const* d_in, const int* in_sizes, int n_in,
                              void* d_out, int out_size, void* d_ws, size_t ws_size,
                              hipStream_t stream) {
    const float* x     = (const float*)d_in[0];
    const float* mu    = (const float*)d_in[1];
    const float* sigma = (const float*)d_in[2];
    float* out = (float*)d_out;

    const size_t nBK   = (size_t)Bb * Kk;            // 768
    const size_t nWu4  = nBK * 800;                  // W frag uint4s per array
    const size_t nXu4  = (size_t)Bb * 64 * 3 * 64;   // 786432 x-frag uint4s (hi only)
    const size_t need_mid  = nWu4 * 16 * 2 + nBK * Nn * 4 + nBK * 4;
    const size_t need_full = need_mid + nXu4 * 16;

    if (ws_size >= need_full) {
        uint4* wsWh = (uint4*)d_ws;
        uint4* wsWl = wsWh + nWu4;
        uint4* Xh   = wsWl + nWu4;
        float* wsV  = (float*)(Xh + nXu4);
        float* wsL  = wsV + nBK * Nn;
        prep_kernel<<<dim3(Bb * Kk), dim3(512), 0, stream>>>(
            sigma, mu, x, wsWh, wsWl, wsV, wsL, Xh, 1);
        ll_kernel2<<<dim3(Bb, Kk), dim3(512), 0, stream>>>(Xh, wsWh, wsWl, wsV, wsL, out);
    } else if (ws_size >= need_mid) {
        uint4* wsWh = (uint4*)d_ws;
        uint4* wsWl = wsWh + nWu4;
        float* wsV  = (float*)(wsWl + nWu4);
        float* wsL  = wsV + nBK * Nn;
        prep_kernel<<<dim3(Bb * Kk), dim3(512), 0, stream>>>(
            sigma, mu, x, wsWh, wsWl, wsV, wsL, (uint4*)nullptr, 0);
        ll_kernel<<<dim3(Bb, 8), dim3(256), 0, stream>>>(x, wsWh, wsWl, wsV, wsL, out);
    } else {
        mvn_ll_fallback<<<dim3(Bb * Kk), dim3(256), 0, stream>>>(x, mu, sigma, out);
    }
}

// Round 14
// 140.530 us; speedup vs baseline: 2.3867x; 1.0627x over previous
//
#include <hip/hip_runtime.h>

#define Bb 64
#define Ss 1000
#define Kk 12
#define Nn 80
#define CTERM 73.51508265637381f   // 0.5 * 80 * log(2*pi)
#define STA 84                     // fp32 LDS stride (336 B, 16B-aligned)

typedef __attribute__((ext_vector_type(8))) short short8;
typedef __attribute__((ext_vector_type(4))) float f32x4;

static __device__ __forceinline__ unsigned short f2bf(float f) {
    unsigned u = __builtin_bit_cast(unsigned, f);
    unsigned r = u + 0x7FFFu + ((u >> 16) & 1u);   // round-to-nearest-even
    return (unsigned short)(r >> 16);
}

// ============ Kernel 1 (R14): R7 8-wave prep; W and x both bf16 HI-ONLY ================
// Error budget (sigma = A A^T/N + I => ||W row||_2 <= 1): bf16 W adds delta_ll ~0.08,
// bf16 x adds ~0.1 — vs threshold 4.08 and an observed error floor of 1.0 that was
// invariant across 3-term/2-term schemes. Wl/Xl pipelines deleted.
__global__ __launch_bounds__(512, 6) void prep_kernel(
    const float* __restrict__ sigma, const float* __restrict__ mu,
    const float* __restrict__ x,
    uint4* __restrict__ wsWh,                              // [768][800] uint4
    float* __restrict__ wsV, float* __restrict__ wsL,
    uint4* __restrict__ Xh, int doX)
{
    __shared__ float Ls[Nn * STA];   // A: working matrix; B: lower=L, upper=W^T
    __shared__ float invd[Nn];
    __shared__ float mus[Nn];
    __shared__ float ldp[8];
    __shared__ float vps[8 * Nn];    // Phase C partial v

    const int bk  = blockIdx.x;
    const int tid = threadIdx.x;
    const int w   = tid >> 6;        // 0..7
    const int l   = tid & 63;
    const int r2  = l + 64;

    // ---- stage sigma: lower + diag-block only (c4 <= r+3) ----
    const float4* sp4 = (const float4*)(sigma + (size_t)bk * Nn * Nn);
    #pragma unroll
    for (int it = 0; it < 4; ++it) {
        int ci = tid + 512 * it;
        if (ci < 1600) {
            int r = ci / 20, c4 = 4 * (ci - 20 * r);
            if (c4 <= r + 3) {
                float4 v = sp4[ci];
                *(float4*)&Ls[r * STA + c4] = v;
            }
        }
    }
    if (tid < Nn) mus[tid] = mu[(size_t)bk * Nn + tid];
    __syncthreads();
    if (tid < Nn) Ls[tid * STA + tid] += 1e-5f;
    __syncthreads();

    // ---- Phase A: blocked Cholesky; master = wave (p&7); 1 barrier/panel ----
    float ldacc = 0.0f;
    for (int p = 0; p < 20; ++p) {
        const int j0 = 4 * p;
        const bool a1 = (l >= j0);
        const bool a2 = (l < 16) && (r2 >= j0);

        if (w == (p & 7)) {
            float B00 = Ls[j0*STA+j0];
            float B10 = Ls[(j0+1)*STA+j0], B11 = Ls[(j0+1)*STA+j0+1];
            float B20 = Ls[(j0+2)*STA+j0], B21 = Ls[(j0+2)*STA+j0+1], B22 = Ls[(j0+2)*STA+j0+2];
            float B30 = Ls[(j0+3)*STA+j0], B31 = Ls[(j0+3)*STA+j0+1], B32 = Ls[(j0+3)*STA+j0+2], B33 = Ls[(j0+3)*STA+j0+3];
            float rv0 = rsqrtf(B00);
            float l10 = B10*rv0, l20 = B20*rv0, l30 = B30*rv0;
            float t11 = fmaf(-l10,l10,B11);                    float rv1 = rsqrtf(t11);
            float l21 = fmaf(-l20,l10,B21)*rv1;
            float l31 = fmaf(-l30,l10,B31)*rv1;
            float t22 = fmaf(-l21,l21,fmaf(-l20,l20,B22));     float rv2 = rsqrtf(t22);
            float l32 = fmaf(-l31,l21,fmaf(-l30,l20,B32))*rv2;
            float t33 = fmaf(-l32,l32,fmaf(-l31,l31,fmaf(-l30,l30,B33)));
            float rv3 = rsqrtf(t33);
            ldacc += 0.5f * (logf(B00) + logf(t11) + logf(t22) + logf(t33));
            if (l == 0) { invd[j0]=rv0; invd[j0+1]=rv1; invd[j0+2]=rv2; invd[j0+3]=rv3; }

            if (a1) {
                float4 a = *(float4*)&Ls[l * STA + j0];
                float b0 = a.x * rv0;
                float b1 = fmaf(-l10, b0, a.y) * rv1;
                float b2 = fmaf(-l21, b1, fmaf(-l20, b0, a.z)) * rv2;
                float b3 = fmaf(-l32, b2, fmaf(-l31, b1, fmaf(-l30, b0, a.w))) * rv3;
                *(float4*)&Ls[l * STA + j0] = make_float4(b0, b1, b2, b3);
            }
            if (a2) {
                float4 a = *(float4*)&Ls[r2 * STA + j0];
                float c0 = a.x * rv0;
                float c1 = fmaf(-l10, c0, a.y) * rv1;
                float c2 = fmaf(-l21, c1, fmaf(-l20, c0, a.z)) * rv2;
                float c3 = fmaf(-l32, c2, fmaf(-l31, c1, fmaf(-l30, c0, a.w))) * rv3;
                *(float4*)&Ls[r2 * STA + j0] = make_float4(c0, c1, c2, c3);
            }
        }
        __syncthreads();   // publish panel solve; the ONLY barrier this panel

        // lower-only update of owned groups (g ≡ w mod 8, g > p); lane l -> row 4g+l
        const int gs0 = p + 1;
        const int g0 = gs0 + ((w - gs0) & 7);
        #pragma unroll 2
        for (int g = g0; g < 20; g += 8) {
            const int cb = 4 * g;
            float4 q0 = *(const float4*)&Ls[(cb+0) * STA + j0];   // L[cb+c][j0..j0+3]
            float4 q1 = *(const float4*)&Ls[(cb+1) * STA + j0];
            float4 q2 = *(const float4*)&Ls[(cb+2) * STA + j0];
            float4 q3 = *(const float4*)&Ls[(cb+3) * STA + j0];
            {
                const int R = cb + l;                              // rows cb..cb+63
                if (R < Nn) {
                    float4 pv = *(const float4*)&Ls[R * STA + j0];
                    float4 t  = *(float4*)&Ls[R * STA + cb];
                    t.x = fmaf(-pv.x,q0.x, fmaf(-pv.y,q0.y, fmaf(-pv.z,q0.z, fmaf(-pv.w,q0.w, t.x))));
                    t.y = fmaf(-pv.x,q1.x, fmaf(-pv.y,q1.y, fmaf(-pv.z,q1.z, fmaf(-pv.w,q1.w, t.y))));
                    t.z = fmaf(-pv.x,q2.x, fmaf(-pv.y,q2.y, fmaf(-pv.z,q2.z, fmaf(-pv.w,q2.w, t.z))));
                    t.w = fmaf(-pv.x,q3.x, fmaf(-pv.y,q3.y, fmaf(-pv.z,q3.z, fmaf(-pv.w,q3.w, t.w))));
                    *(float4*)&Ls[R * STA + cb] = t;
                }
            }
            if (cb + 64 < Nn) {                                    // tail rows cb+64..79 (g<4)
                const int R = cb + 64 + l;
                if (R < Nn) {
                    float4 pv = *(const float4*)&Ls[R * STA + j0];
                    float4 t  = *(float4*)&Ls[R * STA + cb];
                    t.x = fmaf(-pv.x,q0.x, fmaf(-pv.y,q0.y, fmaf(-pv.z,q0.z, fmaf(-pv.w,q0.w, t.x))));
                    t.y = fmaf(-pv.x,q1.x, fmaf(-pv.y,q1.y, fmaf(-pv.z,q1.z, fmaf(-pv.w,q1.w, t.y))));
                    t.z = fmaf(-pv.x,q2.x, fmaf(-pv.y,q2.y, fmaf(-pv.z,q2.z, fmaf(-pv.w,q2.w, t.z))));
                    t.w = fmaf(-pv.x,q3.x, fmaf(-pv.y,q3.y, fmaf(-pv.z,q3.z, fmaf(-pv.w,q3.w, t.w))));
                    *(float4*)&Ls[R * STA + cb] = t;
                }
            }
        }
    }
    if (l == 0) ldp[w] = ldacc;
    __syncthreads();
    if (tid == 0) wsL[bk] = ldp[0]+ldp[1]+ldp[2]+ldp[3]+ldp[4]+ldp[5]+ldp[6]+ldp[7];

    // ---- A->B transition: zero strict-upper storage (W^T region); lower keeps L ----
    for (int i = tid; i < Nn * Nn; i += 512) {
        int r = i / Nn, c = i - Nn * r;
        if (c > r) Ls[r * STA + c] = 0.0f;
    }
    __syncthreads();

    // ---- Phase B: triangular inversion into storage-upper; L read from storage-lower --
    for (int p = 0; p < 20; ++p) {
        const int i0 = 4 * p;
        const bool b1a = (i0 + 3 >= l);
        const bool b2a = (l < 16) && (i0 + 3 >= r2);

        if (w == (p & 7)) {
            float m10 = Ls[(i0+1)*STA + i0];
            float m20 = Ls[(i0+2)*STA + i0];
            float m30 = Ls[(i0+3)*STA + i0];
            float m21 = Ls[(i0+2)*STA + i0+1];
            float m31 = Ls[(i0+3)*STA + i0+1];
            float m32 = Ls[(i0+3)*STA + i0+2];
            float4 iv = *(const float4*)&invd[i0];
            if (b1a) {
                float4 a = *(float4*)&Ls[l * STA + i0];
                if (l >= i0)   // virtual identity rows (diag block)
                    a = make_float4(l==i0?1.f:0.f, l==i0+1?1.f:0.f, l==i0+2?1.f:0.f, l==i0+3?1.f:0.f);
                float w0 = a.x * iv.x;
                float w1 = fmaf(-w0, m10, a.y) * iv.y;
                float w2 = fmaf(-w1, m21, fmaf(-w0, m20, a.z)) * iv.z;
                float w3 = fmaf(-w2, m32, fmaf(-w1, m31, fmaf(-w0, m30, a.w))) * iv.w;
                *(float4*)&Ls[l * STA + i0] = make_float4(w0, w1, w2, w3);
            }
            if (b2a) {
                float4 a = *(float4*)&Ls[r2 * STA + i0];
                if (r2 >= i0)
                    a = make_float4(r2==i0?1.f:0.f, r2==i0+1?1.f:0.f, r2==i0+2?1.f:0.f, r2==i0+3?1.f:0.f);
                float v0 = a.x * iv.x;
                float v1 = fmaf(-v0, m10, a.y) * iv.y;
                float v2 = fmaf(-v1, m21, fmaf(-v0, m20, a.z)) * iv.z;
                float v3 = fmaf(-v2, m32, fmaf(-v1, m31, fmaf(-v0, m30, a.w))) * iv.w;
                *(float4*)&Ls[r2 * STA + i0] = make_float4(v0, v1, v2, v3);
            }
        }
        __syncthreads();   // publish panel solve

        float4 wv = make_float4(0.f,0.f,0.f,0.f), vv = make_float4(0.f,0.f,0.f,0.f);
        if (b1a) wv = *(float4*)&Ls[l * STA + i0];
        if (b2a) vv = *(float4*)&Ls[r2 * STA + i0];
        if (b1a | b2a) {
            const int gs0 = p + 1;
            const int g0 = gs0 + ((w - gs0) & 7);
            for (int g = g0; g < 20; g += 8) {
                float4 q0 = *(const float4*)&Ls[(4*g+0) * STA + i0];  // L[4g+0][i0..i0+3]
                float4 q1 = *(const float4*)&Ls[(4*g+1) * STA + i0];
                float4 q2 = *(const float4*)&Ls[(4*g+2) * STA + i0];
                float4 q3 = *(const float4*)&Ls[(4*g+3) * STA + i0];
                if (b1a) {
                    float4 t = *(float4*)&Ls[l * STA + 4*g];
                    t.x = fmaf(-wv.x,q0.x, fmaf(-wv.y,q0.y, fmaf(-wv.z,q0.z, fmaf(-wv.w,q0.w, t.x))));
                    t.y = fmaf(-wv.x,q1.x, fmaf(-wv.y,q1.y, fmaf(-wv.z,q1.z, fmaf(-wv.w,q1.w, t.y))));
                    t.z = fmaf(-wv.x,q2.x, fmaf(-wv.y,q2.y, fmaf(-wv.z,q2.z, fmaf(-wv.w,q2.w, t.z))));
                    t.w = fmaf(-wv.x,q3.x, fmaf(-wv.y,q3.y, fmaf(-wv.z,q3.z, fmaf(-wv.w,q3.w, t.w))));
                    *(float4*)&Ls[l * STA + 4*g] = t;
                }
                if (b2a) {
                    float4 t = *(float4*)&Ls[r2 * STA + 4*g];
                    t.x = fmaf(-vv.x,q0.x, fmaf(-vv.y,q0.y, fmaf(-vv.z,q0.z, fmaf(-vv.w,q0.w, t.x))));
                    t.y = fmaf(-vv.x,q1.x, fmaf(-vv.y,q1.y, fmaf(-vv.z,q1.z, fmaf(-vv.w,q1.w, t.y))));
                    t.z = fmaf(-vv.x,q2.x, fmaf(-vv.y,q2.y, fmaf(-vv.z,q2.z, fmaf(-vv.w,q2.w, t.z))));
                    t.w = fmaf(-vv.x,q3.x, fmaf(-vv.y,q3.y, fmaf(-vv.z,q3.z, fmaf(-vv.w,q3.w, t.w))));
                    *(float4*)&Ls[r2 * STA + 4*g] = t;
                }
            }
        }
    }
    __syncthreads();

    // ---- Phase C: v = W*mu (mask c<=row since storage-lower holds L, not zeros) ----
    {
        float s1 = 0.f, s2 = 0.f;
        const int c0 = 10 * w;
        #pragma unroll 2
        for (int cc = 0; cc < 10; ++cc) {
            int c = c0 + cc;
            float mc = mus[c];
            float e1 = (c <= l)  ? Ls[c * STA + l]  : 0.f;   // W[l][c]
            s1 = fmaf(e1, mc, s1);
            if (l < 16) {
                float e2 = (c <= r2) ? Ls[c * STA + r2] : 0.f;
                s2 = fmaf(e2, mc, s2);
            }
        }
        vps[w * Nn + l] = s1;
        if (l < 16) vps[w * Nn + r2] = s2;
        __syncthreads();
        if (tid < Nn) {
            float acc = 0.f;
            #pragma unroll
            for (int ww = 0; ww < 8; ++ww) acc += vps[ww * Nn + tid];
            wsV[(size_t)bk * Nn + tid] = acc;
        }
    }

    // ---- Fragment pack (mask m>=kb+j; split 8 ways) — hi only ----
    const int n = l & 15, quad = l >> 4;
    uint4* ph = wsWh + (size_t)bk * 800;
    for (int f = w; f < 10; f += 8) {
        int ks = f / 5, mt = f - 5 * ks;
        int m = 16 * mt + n, kb = 32 * ks + 8 * quad;
        unsigned hh[8];
        #pragma unroll
        for (int j = 0; j < 8; ++j) {
            float wj = (m >= kb + j) ? Ls[(kb + j) * STA + m] : 0.f;   // = W[m][kb+j]
            hh[j] = f2bf(wj);
        }
        ph[f*64 + l] = make_uint4(hh[0]|(hh[1]<<16), hh[2]|(hh[3]<<16), hh[4]|(hh[5]<<16), hh[6]|(hh[7]<<16));
    }
    if (w < 5) {
        int mt = w;
        if (quad < 2) {
            int m = 16 * mt + n, kb = 64 + 8 * quad;
            unsigned hh[8];
            #pragma unroll
            for (int j = 0; j < 8; ++j) {
                float wj = (m >= kb + j) ? Ls[(kb + j) * STA + m] : 0.f;
                hh[j] = f2bf(wj);
            }
            ph[640 + mt*32 + l] = make_uint4(hh[0]|(hh[1]<<16), hh[2]|(hh[3]<<16), hh[4]|(hh[5]<<16), hh[6]|(hh[7]<<16));
        }
    }

    // ---- Fused tail: x -> bf16 HI-ONLY B-fragments; coalesced 1KB/wave bursts ----
    if (doX) {
        const int wid = bk * 8 + w;            // 0..6143 wave-slots
        const int qd = l >> 4, n2 = l & 15;
        #pragma unroll
        for (int it = 0; it < 2; ++it) {
            int G = wid + 6144 * it;            // (b2, sg, ks) groups: 64*63*3 = 12096
            if (G >= 12096) break;
            int b2  = G / 189;
            int rem = G - b2 * 189;
            int sg  = rem / 3, ks = rem - 3 * sg;
            int s   = sg * 16 + n2;
            int k0  = 32 * ks + 8 * qd;
            float d[8] = {0.f,0.f,0.f,0.f,0.f,0.f,0.f,0.f};
            if (s < Ss) {
                const float* xp = x + ((size_t)b2 * Ss + s) * Nn + k0;
                float4 f0 = *(const float4*)xp;
                float4 f1 = *(const float4*)(xp + 4);
                d[0]=f0.x; d[1]=f0.y; d[2]=f0.z; d[3]=f0.w;
                d[4]=f1.x; d[5]=f1.y; d[6]=f1.z; d[7]=f1.w;
            }
            unsigned hh[8];
            #pragma unroll
            for (int j = 0; j < 8; ++j) hh[j] = f2bf(d[j]);
            size_t slot = ((size_t)(b2 * 64 + sg) * 3 + ks) * 64 + l;
            Xh[slot] = make_uint4(hh[0]|(hh[1]<<16), hh[2]|(hh[3]<<16), hh[4]|(hh[5]<<16), hh[6]|(hh[7]<<16));
        }
    }
}

// ============ Kernel 2 (full tier, R14): 8-wave ll2, 1-term MFMA (W hi, X hi) ==========
__global__ __launch_bounds__(512) void ll_kernel2(
    const uint4* __restrict__ Xh,
    const uint4* __restrict__ wsWh,
    const float* __restrict__ wsV, const float* __restrict__ wsL,
    float* __restrict__ out)
{
    __shared__ uint4 WhL[960];   // [0..640): ks=0,1; [640..960): ks=2 expanded
    const int b = blockIdx.x;
    const int k = blockIdx.y;
    const int bk = b * Kk + k;
    const int tid = threadIdx.x;
    const int wv = tid >> 6, lane = tid & 63;
    const int n = lane & 15, quad = lane >> 4;

    const uint4* gh = wsWh + (size_t)bk * 800;
    #pragma unroll
    for (int it = 0; it < 2; ++it) {
        int i = tid + 512 * it;
        if (i < 640) WhL[i] = gh[i];
    }
    if (tid < 320) {
        int mt = tid >> 6, ln = tid & 63, qd = (ln >> 4);
        uint4 vh = make_uint4(0,0,0,0);
        if (qd < 2) vh = gh[640 + mt*32 + ln];
        WhL[640 + tid] = vh;
    }
    __syncthreads();

    const float ld = wsL[bk];
    f32x4 vf[5];
    #pragma unroll
    for (int mt = 0; mt < 5; ++mt)
        vf[mt] = *(const f32x4*)&wsV[(size_t)bk * Nn + 16*mt + 4*quad];

    for (int it = 0; it < 4; ++it) {
        const int sg0 = wv * 8 + it * 2;
        short8 bh[2][3];
        #pragma unroll
        for (int t = 0; t < 2; ++t)
            #pragma unroll
            for (int ks = 0; ks < 3; ++ks) {
                size_t base = ((size_t)(b * 64 + sg0 + t) * 3 + ks) * 64 + lane;
                bh[t][ks] = __builtin_bit_cast(short8, Xh[base]);
            }

        f32x4 acc[2][5];
        #pragma unroll
        for (int t = 0; t < 2; ++t)
            #pragma unroll
            for (int mt = 0; mt < 5; ++mt) acc[t][mt] = (f32x4){0.f,0.f,0.f,0.f};

        #pragma unroll
        for (int ks = 0; ks < 3; ++ks) {
            #pragma unroll
            for (int mt = 0; mt < 5; ++mt) {
                const int fi = (ks < 2) ? (ks*5 + mt)*64 + lane : 640 + mt*64 + lane;
                short8 wh = __builtin_bit_cast(short8, WhL[fi]);
                #pragma unroll
                for (int t = 0; t < 2; ++t)
                    acc[t][mt] = __builtin_amdgcn_mfma_f32_16x16x32_bf16(wh, bh[t][ks], acc[t][mt], 0, 0, 0);
            }
        }

        #pragma unroll
        for (int t = 0; t < 2; ++t) {
            float q2 = 0.f;
            #pragma unroll
            for (int mt = 0; mt < 5; ++mt)
                #pragma unroll
                for (int r = 0; r < 4; ++r) {
                    float y = acc[t][mt][r] - vf[mt][r];
                    q2 = fmaf(y, y, q2);
                }
            q2 += __shfl_xor(q2, 16, 64);
            q2 += __shfl_xor(q2, 32, 64);
            int gs = (sg0 + t) * 16 + n;
            if (lane < 16 && gs < Ss)
                out[((size_t)b * Ss + gs) * Kk + k] = -0.5f * q2 - ld - CTERM;
        }
    }
}

// ============ Kernel 2 (mid tier): zero-LDS 1-term MFMA with in-kernel x conversion ====
__global__ __launch_bounds__(256) void ll_kernel(
    const float* __restrict__ x,
    const uint4* __restrict__ wsWh,
    const float* __restrict__ wsV, const float* __restrict__ wsL,
    float* __restrict__ out)
{
    const int b    = blockIdx.x;
    const int st   = blockIdx.y;
    const int tid  = threadIdx.x;
    const int wv   = tid >> 6, lane = tid & 63;
    const int n    = lane & 15, quad = lane >> 4;
    const int sbase = st * 128 + wv * 32;

    short8 xh[2][3];
    #pragma unroll
    for (int t = 0; t < 2; ++t) {
        int gs = sbase + 16 * t + n;
        #pragma unroll
        for (int ks = 0; ks < 3; ++ks) {
            int kb = 32 * ks + 8 * quad;
            float d[8] = {0.f,0.f,0.f,0.f,0.f,0.f,0.f,0.f};
            if (gs < Ss && kb < Nn) {
                const float* xp = x + ((size_t)b * Ss + gs) * Nn + kb;
                float4 f0 = *(const float4*)xp;
                float4 f1 = *(const float4*)(xp + 4);
                d[0]=f0.x; d[1]=f0.y; d[2]=f0.z; d[3]=f0.w;
                d[4]=f1.x; d[5]=f1.y; d[6]=f1.z; d[7]=f1.w;
            }
            short8 h;
            #pragma unroll
            for (int j = 0; j < 8; ++j) h[j] = (short)f2bf(d[j]);
            xh[t][ks] = h;
        }
    }

    for (int k = 0; k < Kk; ++k) {
        const int bk = b * Kk + k;
        const uint4* ah_p = wsWh + (size_t)bk * 800;

        f32x4 acc[2][5];
        #pragma unroll
        for (int t = 0; t < 2; ++t)
            #pragma unroll
            for (int mt = 0; mt < 5; ++mt) acc[t][mt] = (f32x4){0.f,0.f,0.f,0.f};

        #pragma unroll
        for (int ks = 0; ks < 3; ++ks) {
            short8 ah[5];
            if (ks < 2) {
                #pragma unroll
                for (int mt = 0; mt < 5; ++mt)
                    ah[mt] = __builtin_bit_cast(short8, ah_p[(ks*5 + mt)*64 + lane]);
            } else {
                #pragma unroll
                for (int mt = 0; mt < 5; ++mt) {
                    uint4 zh = make_uint4(0,0,0,0);
                    if (quad < 2) zh = ah_p[640 + mt*32 + lane];
                    ah[mt] = __builtin_bit_cast(short8, zh);
                }
            }
            #pragma unroll
            for (int mt = 0; mt < 5; ++mt)
                #pragma unroll
                for (int t = 0; t < 2; ++t)
                    acc[t][mt] = __builtin_amdgcn_mfma_f32_16x16x32_bf16(ah[mt], xh[t][ks], acc[t][mt], 0, 0, 0);
        }

        float ld = wsL[bk];
        f32x4 vf[5];
        #pragma unroll
        for (int mt = 0; mt < 5; ++mt)
            vf[mt] = *(const f32x4*)&wsV[(size_t)bk * Nn + 16*mt + 4*quad];
        #pragma unroll
        for (int t = 0; t < 2; ++t) {
            float q2 = 0.f;
            #pragma unroll
            for (int mt = 0; mt < 5; ++mt)
                #pragma unroll
                for (int r = 0; r < 4; ++r) {
                    float y = acc[t][mt][r] - vf[mt][r];
                    q2 = fmaf(y, y, q2);
                }
            q2 += __shfl_xor(q2, 16, 64);
            q2 += __shfl_xor(q2, 32, 64);
            int gs = sbase + 16 * t + n;
            if (lane < 16 && gs < Ss)
                out[((size_t)b * Ss + gs) * Kk + k] = -0.5f * q2 - ld - CTERM;
        }
    }
}

// ============ Fallback (ws too small) ==================================================
#define ST1 81
__global__ __launch_bounds__(256) void mvn_ll_fallback(
    const float* __restrict__ x, const float* __restrict__ mu,
    const float* __restrict__ sigma, float* __restrict__ out)
{
    __shared__ float Ls[Nn * ST1];
    __shared__ float invd[Nn];
    __shared__ float mus[Nn];
    __shared__ float logdet_s;

    const int bk = blockIdx.x, b = bk / Kk, k = bk - b * Kk;
    const int tid = threadIdx.x, nt = blockDim.x;

    const float* sp = sigma + (size_t)bk * Nn * Nn;
    for (int t = tid; t < Nn * Nn; t += nt) Ls[(t / Nn) * ST1 + (t % Nn)] = sp[t];
    if (tid < Nn) mus[tid] = mu[(size_t)bk * Nn + tid];
    __syncthreads();
    if (tid < Nn) Ls[tid * ST1 + tid] += 1e-5f;
    __syncthreads();
    for (int j = 0; j < Nn; ++j) {
        if (tid == 0) {
            float d = sqrtf(Ls[j * ST1 + j]);
            Ls[j * ST1 + j] = d; invd[j] = 1.0f / d;
        }
        __syncthreads();
        const float inv = invd[j];
        for (int i = j + 1 + tid; i < Nn; i += nt) Ls[i * ST1 + j] *= inv;
        __syncthreads();
        for (int t = tid; t < Nn * Nn; t += nt) {
            int r = t / Nn, c = t % Nn;
            if (r > j && c > j && c <= r)
                Ls[r * ST1 + c] -= Ls[r * ST1 + j] * Ls[c * ST1 + j];
        }
        __syncthreads();
    }
    if (tid == 0) {
        float a = 0.f; for (int j = 0; j < Nn; ++j) a += logf(Ls[j * ST1 + j]);
        logdet_s = a;
    }
    __syncthreads();
    const float ld = logdet_s;
    for (int s = tid; s < Ss; s += nt) {
        const float4* xp = (const float4*)(x + ((size_t)b * Ss + s) * Nn);
        float a[Nn];
        #pragma unroll
        for (int q = 0; q < Nn / 4; ++q) {
            float4 v = xp[q];
            a[4*q+0] = v.x - mus[4*q+0]; a[4*q+1] = v.y - mus[4*q+1];
            a[4*q+2] = v.z - mus[4*q+2]; a[4*q+3] = v.w - mus[4*q+3];
        }
        #pragma unroll
        for (int i = 0; i < Nn; ++i) {
            float t = a[i];
            #pragma unroll
            for (int j = 0; j < i; ++j) t = fmaf(-Ls[i * ST1 + j], a[j], t);
            a[i] = t * invd[i];
        }
        float quad = 0.f;
        #pragma unroll
        for (int i = 0; i < Nn; ++i) quad = fmaf(a[i], a[i], quad);
        out[((size_t)b * Ss + s) * Kk + k] = -0.5f * quad - ld - CTERM;
    }
}

extern "C" void kernel_launch(void* const* d_in, const int* in_sizes, int n_in,
                              void* d_out, int out_size, void* d_ws, size_t ws_size,
                              hipStream_t stream) {
    const float* x     = (const float*)d_in[0];
    const float* mu    = (const float*)d_in[1];
    const float* sigma = (const float*)d_in[2];
    float* out = (float*)d_out;

    const size_t nBK   = (size_t)Bb * Kk;            // 768
    const size_t nWu4  = nBK * 800;                  // W frag uint4s (hi only)
    const size_t nXu4  = (size_t)Bb * 64 * 3 * 64;   // 786432 x-frag uint4s (hi only)
    const size_t need_mid  = nWu4 * 16 + nBK * Nn * 4 + nBK * 4;
    const size_t need_full = need_mid + nXu4 * 16;

    if (ws_size >= need_full) {
        uint4* wsWh = (uint4*)d_ws;
        uint4* Xh   = wsWh + nWu4;
        float* wsV  = (float*)(Xh + nXu4);
        float* wsL  = wsV + nBK * Nn;
        prep_kernel<<<dim3(Bb * Kk), dim3(512), 0, stream>>>(
            sigma, mu, x, wsWh, wsV, wsL, Xh, 1);
        ll_kernel2<<<dim3(Bb, Kk), dim3(512), 0, stream>>>(Xh, wsWh, wsV, wsL, out);
    } else if (ws_size >= need_mid) {
        uint4* wsWh = (uint4*)d_ws;
        float* wsV  = (float*)(wsWh + nWu4);
        float* wsL  = wsV + nBK * Nn;
        prep_kernel<<<dim3(Bb * Kk), dim3(512), 0, stream>>>(
            sigma, mu, x, wsWh, wsV, wsL, (uint4*)nullptr, 0);
        ll_kernel<<<dim3(Bb, 8), dim3(256), 0, stream>>>(x, wsWh, wsV, wsL, out);
    } else {
        mvn_ll_fallback<<<dim3(Bb * Kk), dim3(256), 0, stream>>>(x, mu, sigma, out);
    }
}

// Round 15
// 138.784 us; speedup vs baseline: 2.4167x; 1.0126x over previous
//
#include <hip/hip_runtime.h>

#define Bb 64
#define Ss 1000
#define Kk 12
#define Nn 80
#define CTERM 73.51508265637381f   // 0.5 * 80 * log(2*pi)
#define STA 84                     // fp32 LDS stride (336 B, 16B-aligned)

typedef __attribute__((ext_vector_type(8))) short short8;
typedef __attribute__((ext_vector_type(4))) float f32x4;

static __device__ __forceinline__ unsigned short f2bf(float f) {
    unsigned u = __builtin_bit_cast(unsigned, f);
    unsigned r = u + 0x7FFFu + ((u >> 16) & 1u);   // round-to-nearest-even
    return (unsigned short)(r >> 16);
}

// ============ Kernel 1 (R15): INTERLEAVED Cholesky+inversion, 21 phases (was 40) =======
// Phase p: {A-solve p (wave p&7) || B-solve p-1 (wave (p-1)&7)} -> barrier ->
//          {A-update p || B-update p-1} for all waves on owned groups (g = w mod 8).
// B uses first-touch-zero/identity (R8-validated) — the A->B zeroing pass is deleted.
// All region-disjointness and wave-synchronous hand-offs verified (see session notes).
// W and x are bf16 HI-ONLY (R13/R14 error budget: ||W row|| <= 1, delta_ll << 4.08).
__global__ __launch_bounds__(512, 6) void prep_kernel(
    const float* __restrict__ sigma, const float* __restrict__ mu,
    const float* __restrict__ x,
    uint4* __restrict__ wsWh,                              // [768][800] uint4
    float* __restrict__ wsV, float* __restrict__ wsL,
    uint4* __restrict__ Xh, int doX)
{
    __shared__ float Ls[Nn * STA];   // lower = L (Phase A), upper = W^T (Phase B)
    __shared__ float invd[Nn];
    __shared__ float mus[Nn];
    __shared__ float ldp[8];
    __shared__ float vps[8 * Nn];    // Phase C partial v

    const int bk  = blockIdx.x;
    const int tid = threadIdx.x;
    const int w   = tid >> 6;        // 0..7
    const int l   = tid & 63;
    const int r2  = l + 64;

    // ---- stage sigma: lower + diag-block only (c4 <= r+3) ----
    const float4* sp4 = (const float4*)(sigma + (size_t)bk * Nn * Nn);
    #pragma unroll
    for (int it = 0; it < 4; ++it) {
        int ci = tid + 512 * it;
        if (ci < 1600) {
            int r = ci / 20, c4 = 4 * (ci - 20 * r);
            if (c4 <= r + 3) {
                float4 v = sp4[ci];
                *(float4*)&Ls[r * STA + c4] = v;
            }
        }
    }
    if (tid < Nn) mus[tid] = mu[(size_t)bk * Nn + tid];
    __syncthreads();
    if (tid < Nn) Ls[tid * STA + tid] += 1e-5f;
    __syncthreads();

    // ---- Interleaved A (Cholesky) + B (inversion): 21 phases, 1 barrier each ----
    float ldacc = 0.0f;
    for (int p = 0; p <= 20; ++p) {
        const int j0 = 4 * p;            // A panel (valid p<20)
        const int i0 = 4 * (p - 1);      // B panel (valid p>=1)

        // ---- A-solve panel p (master wave p&7) ----
        if (p < 20 && w == (p & 7)) {
            float B00 = Ls[j0*STA+j0];
            float B10 = Ls[(j0+1)*STA+j0], B11 = Ls[(j0+1)*STA+j0+1];
            float B20 = Ls[(j0+2)*STA+j0], B21 = Ls[(j0+2)*STA+j0+1], B22 = Ls[(j0+2)*STA+j0+2];
            float B30 = Ls[(j0+3)*STA+j0], B31 = Ls[(j0+3)*STA+j0+1], B32 = Ls[(j0+3)*STA+j0+2], B33 = Ls[(j0+3)*STA+j0+3];
            float rv0 = rsqrtf(B00);
            float l10 = B10*rv0, l20 = B20*rv0, l30 = B30*rv0;
            float t11 = fmaf(-l10,l10,B11);                    float rv1 = rsqrtf(t11);
            float l21 = fmaf(-l20,l10,B21)*rv1;
            float l31 = fmaf(-l30,l10,B31)*rv1;
            float t22 = fmaf(-l21,l21,fmaf(-l20,l20,B22));     float rv2 = rsqrtf(t22);
            float l32 = fmaf(-l31,l21,fmaf(-l30,l20,B32))*rv2;
            float t33 = fmaf(-l32,l32,fmaf(-l31,l31,fmaf(-l30,l30,B33)));
            float rv3 = rsqrtf(t33);
            ldacc += 0.5f * (logf(B00) + logf(t11) + logf(t22) + logf(t33));
            if (l == 0) { invd[j0]=rv0; invd[j0+1]=rv1; invd[j0+2]=rv2; invd[j0+3]=rv3; }

            if (l >= j0) {
                float4 a = *(float4*)&Ls[l * STA + j0];
                float b0 = a.x * rv0;
                float b1 = fmaf(-l10, b0, a.y) * rv1;
                float b2 = fmaf(-l21, b1, fmaf(-l20, b0, a.z)) * rv2;
                float b3 = fmaf(-l32, b2, fmaf(-l31, b1, fmaf(-l30, b0, a.w))) * rv3;
                *(float4*)&Ls[l * STA + j0] = make_float4(b0, b1, b2, b3);
            }
            if (l < 16 && r2 >= j0) {
                float4 a = *(float4*)&Ls[r2 * STA + j0];
                float c0 = a.x * rv0;
                float c1 = fmaf(-l10, c0, a.y) * rv1;
                float c2 = fmaf(-l21, c1, fmaf(-l20, c0, a.z)) * rv2;
                float c3 = fmaf(-l32, c2, fmaf(-l31, c1, fmaf(-l30, c0, a.w))) * rv3;
                *(float4*)&Ls[r2 * STA + j0] = make_float4(c0, c1, c2, c3);
            }
        }

        // ---- B-solve panel p-1 (master wave (p-1)&7); first-touch identity ----
        if (p >= 1 && w == ((p - 1) & 7)) {
            float m10 = Ls[(i0+1)*STA + i0];
            float m20 = Ls[(i0+2)*STA + i0];
            float m30 = Ls[(i0+3)*STA + i0];
            float m21 = Ls[(i0+2)*STA + i0+1];
            float m31 = Ls[(i0+3)*STA + i0+1];
            float m32 = Ls[(i0+3)*STA + i0+2];
            float4 iv = *(const float4*)&invd[i0];
            if (i0 + 3 >= l) {
                float4 a;
                if (l >= i0)
                    a = make_float4(l==i0?1.f:0.f, l==i0+1?1.f:0.f, l==i0+2?1.f:0.f, l==i0+3?1.f:0.f);
                else
                    a = *(float4*)&Ls[l * STA + i0];
                float w0 = a.x * iv.x;
                float w1 = fmaf(-w0, m10, a.y) * iv.y;
                float w2 = fmaf(-w1, m21, fmaf(-w0, m20, a.z)) * iv.z;
                float w3 = fmaf(-w2, m32, fmaf(-w1, m31, fmaf(-w0, m30, a.w))) * iv.w;
                *(float4*)&Ls[l * STA + i0] = make_float4(w0, w1, w2, w3);
            }
            if (l < 16 && i0 + 3 >= r2) {
                float4 a;
                if (r2 >= i0)
                    a = make_float4(r2==i0?1.f:0.f, r2==i0+1?1.f:0.f, r2==i0+2?1.f:0.f, r2==i0+3?1.f:0.f);
                else
                    a = *(float4*)&Ls[r2 * STA + i0];
                float v0 = a.x * iv.x;
                float v1 = fmaf(-v0, m10, a.y) * iv.y;
                float v2 = fmaf(-v1, m21, fmaf(-v0, m20, a.z)) * iv.z;
                float v3 = fmaf(-v2, m32, fmaf(-v1, m31, fmaf(-v0, m30, a.w))) * iv.w;
                *(float4*)&Ls[r2 * STA + i0] = make_float4(v0, v1, v2, v3);
            }
        }
        __syncthreads();   // the ONLY barrier this phase

        // ---- A-update panel p: lower-only, lane l -> row 4g+l (owned g = w mod 8) ----
        if (p < 20) {
            const int gs0 = p + 1;
            const int g0 = gs0 + ((w - gs0) & 7);
            for (int g = g0; g < 20; g += 8) {
                const int cb = 4 * g;
                float4 q0 = *(const float4*)&Ls[(cb+0) * STA + j0];
                float4 q1 = *(const float4*)&Ls[(cb+1) * STA + j0];
                float4 q2 = *(const float4*)&Ls[(cb+2) * STA + j0];
                float4 q3 = *(const float4*)&Ls[(cb+3) * STA + j0];
                {
                    const int R = cb + l;
                    if (R < Nn) {
                        float4 pv = *(const float4*)&Ls[R * STA + j0];
                        float4 t  = *(float4*)&Ls[R * STA + cb];
                        t.x = fmaf(-pv.x,q0.x, fmaf(-pv.y,q0.y, fmaf(-pv.z,q0.z, fmaf(-pv.w,q0.w, t.x))));
                        t.y = fmaf(-pv.x,q1.x, fmaf(-pv.y,q1.y, fmaf(-pv.z,q1.z, fmaf(-pv.w,q1.w, t.y))));
                        t.z = fmaf(-pv.x,q2.x, fmaf(-pv.y,q2.y, fmaf(-pv.z,q2.z, fmaf(-pv.w,q2.w, t.z))));
                        t.w = fmaf(-pv.x,q3.x, fmaf(-pv.y,q3.y, fmaf(-pv.z,q3.z, fmaf(-pv.w,q3.w, t.w))));
                        *(float4*)&Ls[R * STA + cb] = t;
                    }
                }
                if (cb + 64 < Nn) {
                    const int R = cb + 64 + l;
                    if (R < Nn) {
                        float4 pv = *(const float4*)&Ls[R * STA + j0];
                        float4 t  = *(float4*)&Ls[R * STA + cb];
                        t.x = fmaf(-pv.x,q0.x, fmaf(-pv.y,q0.y, fmaf(-pv.z,q0.z, fmaf(-pv.w,q0.w, t.x))));
                        t.y = fmaf(-pv.x,q1.x, fmaf(-pv.y,q1.y, fmaf(-pv.z,q1.z, fmaf(-pv.w,q1.w, t.y))));
                        t.z = fmaf(-pv.x,q2.x, fmaf(-pv.y,q2.y, fmaf(-pv.z,q2.z, fmaf(-pv.w,q2.w, t.z))));
                        t.w = fmaf(-pv.x,q3.x, fmaf(-pv.y,q3.y, fmaf(-pv.z,q3.z, fmaf(-pv.w,q3.w, t.w))));
                        *(float4*)&Ls[R * STA + cb] = t;
                    }
                }
            }
        }

        // ---- B-update panel p-1: upper, first-touch zero (owned g = w mod 8, g >= p) --
        if (p >= 1) {
            const bool b1a = (i0 + 3 >= l);
            const bool b2a = (l < 16) && (i0 + 3 >= r2);
            if (b1a | b2a) {
                float4 wv = make_float4(0.f,0.f,0.f,0.f), vv = make_float4(0.f,0.f,0.f,0.f);
                if (b1a) wv = *(float4*)&Ls[l * STA + i0];
                if (b2a) vv = *(float4*)&Ls[r2 * STA + i0];
                const int gs0 = p;
                const int g0 = gs0 + ((w - gs0) & 7);
                for (int g = g0; g < 20; g += 8) {
                    const int cb = 4 * g;
                    float4 q0 = *(const float4*)&Ls[(cb+0) * STA + i0];
                    float4 q1 = *(const float4*)&Ls[(cb+1) * STA + i0];
                    float4 q2 = *(const float4*)&Ls[(cb+2) * STA + i0];
                    float4 q3 = *(const float4*)&Ls[(cb+3) * STA + i0];
                    if (b1a) {
                        float4 t;
                        if (l >= i0) t = make_float4(0.f, 0.f, 0.f, 0.f);   // first touch
                        else         t = *(float4*)&Ls[l * STA + cb];
                        t.x = fmaf(-wv.x,q0.x, fmaf(-wv.y,q0.y, fmaf(-wv.z,q0.z, fmaf(-wv.w,q0.w, t.x))));
                        t.y = fmaf(-wv.x,q1.x, fmaf(-wv.y,q1.y, fmaf(-wv.z,q1.z, fmaf(-wv.w,q1.w, t.y))));
                        t.z = fmaf(-wv.x,q2.x, fmaf(-wv.y,q2.y, fmaf(-wv.z,q2.z, fmaf(-wv.w,q2.w, t.z))));
                        t.w = fmaf(-wv.x,q3.x, fmaf(-wv.y,q3.y, fmaf(-wv.z,q3.z, fmaf(-wv.w,q3.w, t.w))));
                        *(float4*)&Ls[l * STA + cb] = t;
                    }
                    if (b2a) {
                        float4 t;
                        if (r2 >= i0) t = make_float4(0.f, 0.f, 0.f, 0.f);
                        else          t = *(float4*)&Ls[r2 * STA + cb];
                        t.x = fmaf(-vv.x,q0.x, fmaf(-vv.y,q0.y, fmaf(-vv.z,q0.z, fmaf(-vv.w,q0.w, t.x))));
                        t.y = fmaf(-vv.x,q1.x, fmaf(-vv.y,q1.y, fmaf(-vv.z,q1.z, fmaf(-vv.w,q1.w, t.y))));
                        t.z = fmaf(-vv.x,q2.x, fmaf(-vv.y,q2.y, fmaf(-vv.z,q2.z, fmaf(-vv.w,q2.w, t.z))));
                        t.w = fmaf(-vv.x,q3.x, fmaf(-vv.y,q3.y, fmaf(-vv.z,q3.z, fmaf(-vv.w,q3.w, t.w))));
                        *(float4*)&Ls[r2 * STA + cb] = t;
                    }
                }
            }
        }
    }
    if (l == 0) ldp[w] = ldacc;
    __syncthreads();
    if (tid == 0) wsL[bk] = ldp[0]+ldp[1]+ldp[2]+ldp[3]+ldp[4]+ldp[5]+ldp[6]+ldp[7];
    __syncthreads();

    // ---- Phase C: v = W*mu (mask c<=row since storage-lower holds L, not zeros) ----
    {
        float s1 = 0.f, s2 = 0.f;
        const int c0 = 10 * w;
        #pragma unroll 2
        for (int cc = 0; cc < 10; ++cc) {
            int c = c0 + cc;
            float mc = mus[c];
            float e1 = (c <= l)  ? Ls[c * STA + l]  : 0.f;   // W[l][c]
            s1 = fmaf(e1, mc, s1);
            if (l < 16) {
                float e2 = (c <= r2) ? Ls[c * STA + r2] : 0.f;
                s2 = fmaf(e2, mc, s2);
            }
        }
        vps[w * Nn + l] = s1;
        if (l < 16) vps[w * Nn + r2] = s2;
        __syncthreads();
        if (tid < Nn) {
            float acc = 0.f;
            #pragma unroll
            for (int ww = 0; ww < 8; ++ww) acc += vps[ww * Nn + tid];
            wsV[(size_t)bk * Nn + tid] = acc;
        }
    }

    // ---- Fragment pack (mask m>=kb+j; split 8 ways) — hi only ----
    const int n = l & 15, quad = l >> 4;
    uint4* ph = wsWh + (size_t)bk * 800;
    for (int f = w; f < 10; f += 8) {
        int ks = f / 5, mt = f - 5 * ks;
        int m = 16 * mt + n, kb = 32 * ks + 8 * quad;
        unsigned hh[8];
        #pragma unroll
        for (int j = 0; j < 8; ++j) {
            float wj = (m >= kb + j) ? Ls[(kb + j) * STA + m] : 0.f;   // = W[m][kb+j]
            hh[j] = f2bf(wj);
        }
        ph[f*64 + l] = make_uint4(hh[0]|(hh[1]<<16), hh[2]|(hh[3]<<16), hh[4]|(hh[5]<<16), hh[6]|(hh[7]<<16));
    }
    if (w < 5) {
        int mt = w;
        if (quad < 2) {
            int m = 16 * mt + n, kb = 64 + 8 * quad;
            unsigned hh[8];
            #pragma unroll
            for (int j = 0; j < 8; ++j) {
                float wj = (m >= kb + j) ? Ls[(kb + j) * STA + m] : 0.f;
                hh[j] = f2bf(wj);
            }
            ph[640 + mt*32 + l] = make_uint4(hh[0]|(hh[1]<<16), hh[2]|(hh[3]<<16), hh[4]|(hh[5]<<16), hh[6]|(hh[7]<<16));
        }
    }

    // ---- Fused tail: x -> bf16 HI-ONLY B-fragments; coalesced 1KB/wave bursts ----
    if (doX) {
        const int wid = bk * 8 + w;            // 0..6143 wave-slots
        const int qd = l >> 4, n2 = l & 15;
        #pragma unroll
        for (int it = 0; it < 2; ++it) {
            int G = wid + 6144 * it;            // (b2, sg, ks) groups: 64*63*3 = 12096
            if (G >= 12096) break;
            int b2  = G / 189;
            int rem = G - b2 * 189;
            int sg  = rem / 3, ks = rem - 3 * sg;
            int s   = sg * 16 + n2;
            int k0  = 32 * ks + 8 * qd;
            float d[8] = {0.f,0.f,0.f,0.f,0.f,0.f,0.f,0.f};
            if (s < Ss) {
                const float* xp = x + ((size_t)b2 * Ss + s) * Nn + k0;
                float4 f0 = *(const float4*)xp;
                float4 f1 = *(const float4*)(xp + 4);
                d[0]=f0.x; d[1]=f0.y; d[2]=f0.z; d[3]=f0.w;
                d[4]=f1.x; d[5]=f1.y; d[6]=f1.z; d[7]=f1.w;
            }
            unsigned hh[8];
            #pragma unroll
            for (int j = 0; j < 8; ++j) hh[j] = f2bf(d[j]);
            size_t slot = ((size_t)(b2 * 64 + sg) * 3 + ks) * 64 + l;
            Xh[slot] = make_uint4(hh[0]|(hh[1]<<16), hh[2]|(hh[3]<<16), hh[4]|(hh[5]<<16), hh[6]|(hh[7]<<16));
        }
    }
}

// ============ Kernel 2 (full tier, R14-validated): 8-wave ll2, 1-term MFMA =============
__global__ __launch_bounds__(512) void ll_kernel2(
    const uint4* __restrict__ Xh,
    const uint4* __restrict__ wsWh,
    const float* __restrict__ wsV, const float* __restrict__ wsL,
    float* __restrict__ out)
{
    __shared__ uint4 WhL[960];   // [0..640): ks=0,1; [640..960): ks=2 expanded
    const int b = blockIdx.x;
    const int k = blockIdx.y;
    const int bk = b * Kk + k;
    const int tid = threadIdx.x;
    const int wv = tid >> 6, lane = tid & 63;
    const int n = lane & 15, quad = lane >> 4;

    const uint4* gh = wsWh + (size_t)bk * 800;
    #pragma unroll
    for (int it = 0; it < 2; ++it) {
        int i = tid + 512 * it;
        if (i < 640) WhL[i] = gh[i];
    }
    if (tid < 320) {
        int mt = tid >> 6, ln = tid & 63, qd = (ln >> 4);
        uint4 vh = make_uint4(0,0,0,0);
        if (qd < 2) vh = gh[640 + mt*32 + ln];
        WhL[640 + tid] = vh;
    }
    __syncthreads();

    const float ld = wsL[bk];
    f32x4 vf[5];
    #pragma unroll
    for (int mt = 0; mt < 5; ++mt)
        vf[mt] = *(const f32x4*)&wsV[(size_t)bk * Nn + 16*mt + 4*quad];

    for (int it = 0; it < 4; ++it) {
        const int sg0 = wv * 8 + it * 2;
        short8 bh[2][3];
        #pragma unroll
        for (int t = 0; t < 2; ++t)
            #pragma unroll
            for (int ks = 0; ks < 3; ++ks) {
                size_t base = ((size_t)(b * 64 + sg0 + t) * 3 + ks) * 64 + lane;
                bh[t][ks] = __builtin_bit_cast(short8, Xh[base]);
            }

        f32x4 acc[2][5];
        #pragma unroll
        for (int t = 0; t < 2; ++t)
            #pragma unroll
            for (int mt = 0; mt < 5; ++mt) acc[t][mt] = (f32x4){0.f,0.f,0.f,0.f};

        #pragma unroll
        for (int ks = 0; ks < 3; ++ks) {
            #pragma unroll
            for (int mt = 0; mt < 5; ++mt) {
                const int fi = (ks < 2) ? (ks*5 + mt)*64 + lane : 640 + mt*64 + lane;
                short8 wh = __builtin_bit_cast(short8, WhL[fi]);
                #pragma unroll
                for (int t = 0; t < 2; ++t)
                    acc[t][mt] = __builtin_amdgcn_mfma_f32_16x16x32_bf16(wh, bh[t][ks], acc[t][mt], 0, 0, 0);
            }
        }

        #pragma unroll
        for (int t = 0; t < 2; ++t) {
            float q2 = 0.f;
            #pragma unroll
            for (int mt = 0; mt < 5; ++mt)
                #pragma unroll
                for (int r = 0; r < 4; ++r) {
                    float y = acc[t][mt][r] - vf[mt][r];
                    q2 = fmaf(y, y, q2);
                }
            q2 += __shfl_xor(q2, 16, 64);
            q2 += __shfl_xor(q2, 32, 64);
            int gs = (sg0 + t) * 16 + n;
            if (lane < 16 && gs < Ss)
                out[((size_t)b * Ss + gs) * Kk + k] = -0.5f * q2 - ld - CTERM;
        }
    }
}

// ============ Kernel 2 (mid tier): zero-LDS 1-term MFMA with in-kernel x conversion ====
__global__ __launch_bounds__(256) void ll_kernel(
    const float* __restrict__ x,
    const uint4* __restrict__ wsWh,
    const float* __restrict__ wsV, const float* __restrict__ wsL,
    float* __restrict__ out)
{
    const int b    = blockIdx.x;
    const int st   = blockIdx.y;
    const int tid  = threadIdx.x;
    const int wv   = tid >> 6, lane = tid & 63;
    const int n    = lane & 15, quad = lane >> 4;
    const int sbase = st * 128 + wv * 32;

    short8 xh[2][3];
    #pragma unroll
    for (int t = 0; t < 2; ++t) {
        int gs = sbase + 16 * t + n;
        #pragma unroll
        for (int ks = 0; ks < 3; ++ks) {
            int kb = 32 * ks + 8 * quad;
            float d[8] = {0.f,0.f,0.f,0.f,0.f,0.f,0.f,0.f};
            if (gs < Ss && kb < Nn) {
                const float* xp = x + ((size_t)b * Ss + gs) * Nn + kb;
                float4 f0 = *(const float4*)xp;
                float4 f1 = *(const float4*)(xp + 4);
                d[0]=f0.x; d[1]=f0.y; d[2]=f0.z; d[3]=f0.w;
                d[4]=f1.x; d[5]=f1.y; d[6]=f1.z; d[7]=f1.w;
            }
            short8 h;
            #pragma unroll
            for (int j = 0; j < 8; ++j) h[j] = (short)f2bf(d[j]);
            xh[t][ks] = h;
        }
    }

    for (int k = 0; k < Kk; ++k) {
        const int bk = b * Kk + k;
        const uint4* ah_p = wsWh + (size_t)bk * 800;

        f32x4 acc[2][5];
        #pragma unroll
        for (int t = 0; t < 2; ++t)
            #pragma unroll
            for (int mt = 0; mt < 5; ++mt) acc[t][mt] = (f32x4){0.f,0.f,0.f,0.f};

        #pragma unroll
        for (int ks = 0; ks < 3; ++ks) {
            short8 ah[5];
            if (ks < 2) {
                #pragma unroll
                for (int mt = 0; mt < 5; ++mt)
                    ah[mt] = __builtin_bit_cast(short8, ah_p[(ks*5 + mt)*64 + lane]);
            } else {
                #pragma unroll
                for (int mt = 0; mt < 5; ++mt) {
                    uint4 zh = make_uint4(0,0,0,0);
                    if (quad < 2) zh = ah_p[640 + mt*32 + lane];
                    ah[mt] = __builtin_bit_cast(short8, zh);
                }
            }
            #pragma unroll
            for (int mt = 0; mt < 5; ++mt)
                #pragma unroll
                for (int t = 0; t < 2; ++t)
                    acc[t][mt] = __builtin_amdgcn_mfma_f32_16x16x32_bf16(ah[mt], xh[t][ks], acc[t][mt], 0, 0, 0);
        }

        float ld = wsL[bk];
        f32x4 vf[5];
        #pragma unroll
        for (int mt = 0; mt < 5; ++mt)
            vf[mt] = *(const f32x4*)&wsV[(size_t)bk * Nn + 16*mt + 4*quad];
        #pragma unroll
        for (int t = 0; t < 2; ++t) {
            float q2 = 0.f;
            #pragma unroll
            for (int mt = 0; mt < 5; ++mt)
                #pragma unroll
                for (int r = 0; r < 4; ++r) {
                    float y = acc[t][mt][r] - vf[mt][r];
                    q2 = fmaf(y, y, q2);
                }
            q2 += __shfl_xor(q2, 16, 64);
            q2 += __shfl_xor(q2, 32, 64);
            int gs = sbase + 16 * t + n;
            if (lane < 16 && gs < Ss)
                out[((size_t)b * Ss + gs) * Kk + k] = -0.5f * q2 - ld - CTERM;
        }
    }
}

// ============ Fallback (ws too small) ==================================================
#define ST1 81
__global__ __launch_bounds__(256) void mvn_ll_fallback(
    const float* __restrict__ x, const float* __restrict__ mu,
    const float* __restrict__ sigma, float* __restrict__ out)
{
    __shared__ float Ls[Nn * ST1];
    __shared__ float invd[Nn];
    __shared__ float mus[Nn];
    __shared__ float logdet_s;

    const int bk = blockIdx.x, b = bk / Kk, k = bk - b * Kk;
    const int tid = threadIdx.x, nt = blockDim.x;

    const float* sp = sigma + (size_t)bk * Nn * Nn;
    for (int t = tid; t < Nn * Nn; t += nt) Ls[(t / Nn) * ST1 + (t % Nn)] = sp[t];
    if (tid < Nn) mus[tid] = mu[(size_t)bk * Nn + tid];
    __syncthreads();
    if (tid < Nn) Ls[tid * ST1 + tid] += 1e-5f;
    __syncthreads();
    for (int j = 0; j < Nn; ++j) {
        if (tid == 0) {
            float d = sqrtf(Ls[j * ST1 + j]);
            Ls[j * ST1 + j] = d; invd[j] = 1.0f / d;
        }
        __syncthreads();
        const float inv = invd[j];
        for (int i = j + 1 + tid; i < Nn; i += nt) Ls[i * ST1 + j] *= inv;
        __syncthreads();
        for (int t = tid; t < Nn * Nn; t += nt) {
            int r = t / Nn, c = t % Nn;
            if (r > j && c > j && c <= r)
                Ls[r * ST1 + c] -= Ls[r * ST1 + j] * Ls[c * ST1 + j];
        }
        __syncthreads();
    }
    if (tid == 0) {
        float a = 0.f; for (int j = 0; j < Nn; ++j) a += logf(Ls[j * ST1 + j]);
        logdet_s = a;
    }
    __syncthreads();
    const float ld = logdet_s;
    for (int s = tid; s < Ss; s += nt) {
        const float4* xp = (const float4*)(x + ((size_t)b * Ss + s) * Nn);
        float a[Nn];
        #pragma unroll
        for (int q = 0; q < Nn / 4; ++q) {
            float4 v = xp[q];
            a[4*q+0] = v.x - mus[4*q+0]; a[4*q+1] = v.y - mus[4*q+1];
            a[4*q+2] = v.z - mus[4*q+2]; a[4*q+3] = v.w - mus[4*q+3];
        }
        #pragma unroll
        for (int i = 0; i < Nn; ++i) {
            float t = a[i];
            #pragma unroll
            for (int j = 0; j < i; ++j) t = fmaf(-Ls[i * ST1 + j], a[j], t);
            a[i] = t * invd[i];
        }
        float quad = 0.f;
        #pragma unroll
        for (int i = 0; i < Nn; ++i) quad = fmaf(a[i], a[i], quad);
        out[((size_t)b * Ss + s) * Kk + k] = -0.5f * quad - ld - CTERM;
    }
}

extern "C" void kernel_launch(void* const* d_in, const int* in_sizes, int n_in,
                              void* d_out, int out_size, void* d_ws, size_t ws_size,
                              hipStream_t stream) {
    const float* x     = (const float*)d_in[0];
    const float* mu    = (const float*)d_in[1];
    const float* sigma = (const float*)d_in[2];
    float* out = (float*)d_out;

    const size_t nBK   = (size_t)Bb * Kk;            // 768
    const size_t nWu4  = nBK * 800;                  // W frag uint4s (hi only)
    const size_t nXu4  = (size_t)Bb * 64 * 3 * 64;   // 786432 x-frag uint4s (hi only)
    const size_t need_mid  = nWu4 * 16 + nBK * Nn * 4 + nBK * 4;
    const size_t need_full = need_mid + nXu4 * 16;

    if (ws_size >= need_full) {
        uint4* wsWh = (uint4*)d_ws;
        uint4* Xh   = wsWh + nWu4;
        float* wsV  = (float*)(Xh + nXu4);
        float* wsL  = wsV + nBK * Nn;
        prep_kernel<<<dim3(Bb * Kk), dim3(512), 0, stream>>>(
            sigma, mu, x, wsWh, wsV, wsL, Xh, 1);
        ll_kernel2<<<dim3(Bb, Kk), dim3(512), 0, stream>>>(Xh, wsWh, wsV, wsL, out);
    } else if (ws_size >= need_mid) {
        uint4* wsWh = (uint4*)d_ws;
        float* wsV  = (float*)(wsWh + nWu4);
        float* wsL  = wsV + nBK * Nn;
        prep_kernel<<<dim3(Bb * Kk), dim3(512), 0, stream>>>(
            sigma, mu, x, wsWh, wsV, wsL, (uint4*)nullptr, 0);
        ll_kernel<<<dim3(Bb, 8), dim3(256), 0, stream>>>(x, wsWh, wsV, wsL, out);
    } else {
        mvn_ll_fallback<<<dim3(Bb * Kk), dim3(256), 0, stream>>>(x, mu, sigma, out);
    }
}